// Round 15
// baseline (240.459 us; speedup 1.0000x reference)
//
#include <hip/hip_runtime.h>

// ---------------------------------------------------------------------------
// Problem constants
// ---------------------------------------------------------------------------
#define V_PREV 16384
#define V_NEXT 65536
#define F_IN   512
#define F_OUT  256
#define NNZ_UP 65536
#define N_EDGE 524288

using f32x4 = __attribute__((ext_vector_type(4))) float;
using bfrag = __attribute__((ext_vector_type(8))) short;   // 8 x bf16

#define LSTR 36   // LDS row stride in shorts: bank base 18*row mod 32 -> <=2-way

__device__ __forceinline__ ushort f2bf(float f) {
    union { float f; unsigned u; } v; v.f = f;
    unsigned r = (v.u + 0x7FFFu + ((v.u >> 16) & 1u)) >> 16;
    return (ushort)r;
}
__device__ __forceinline__ float bf2f(ushort h) {
    union { unsigned u; float f; } v; v.u = ((unsigned)h) << 16; return v.f;
}

// ---------------------------------------------------------------------------
// Mega K1: weight prep (0..1023) + invert_up (1024..1279)
//        + hist cnt (1280..3327) + bn0_part (3328..3839)
// (cnt/psum1s/psq1s zeroed by memsetAsync BEFORE this kernel)
// ---------------------------------------------------------------------------
__global__ void mega_prep_kernel(const float* __restrict__ Wres,
                                 const float* __restrict__ Ui0W, const float* __restrict__ Uj0W,
                                 const float* __restrict__ Ui1W, const float* __restrict__ Uj1W,
                                 const float* __restrict__ Ui1b, const float* __restrict__ bres,
                                 const int* __restrict__ up_row, const int* __restrict__ up_col,
                                 const float* __restrict__ up_val,
                                 const int* __restrict__ dst,
                                 const float* __restrict__ x,
                                 ushort* __restrict__ WresT, ushort* __restrict__ W0t,
                                 ushort* __restrict__ W1cat, float* __restrict__ biasUi,
                                 int* __restrict__ colof, float* __restrict__ valof,
                                 int* __restrict__ cnt,
                                 float* __restrict__ psum0, float* __restrict__ psq0)
{
    int b = blockIdx.x, t = threadIdx.x;
    if (b < 1024) {
        int i = b * 256 + t;                      // 0 .. 262143
        if (i < 256 * 512) {
            int n = i / 512, k = i % 512;
            WresT[i] = f2bf(Wres[k * 256 + n]);
            W1cat[i] = f2bf(k < 256 ? Ui1W[k * 256 + n] : Uj1W[(k - 256) * 256 + n]);
        }
        {
            int n = i / 512, k = i % 512;
            W0t[i] = f2bf(n < 256 ? Uj0W[k * 256 + n] : Ui0W[k * 256 + (n - 256)]);
        }
        if (i < 256) biasUi[i] = Ui1b[i] + bres[i];
    } else if (b < 1280) {
        int k = (b - 1024) * 256 + t;             // 0 .. 65535
        int r = up_row[k];
        colof[r] = up_col[k];
        valof[r] = up_val[k];
    } else if (b < 3328) {
        int e = (b - 1280) * 256 + t;             // 0 .. 524287
        atomicAdd(&cnt[dst[e]], 1);
    } else {
        int blk = b - 3328;                        // 0..511, 32 rows each
        float s0 = 0, s1 = 0, q0 = 0, q1 = 0;
        for (int r = 0; r < 32; r++) {
            size_t base = ((size_t)blk * 32 + r) * 512;
            float a = x[base + t], bb = x[base + t + 256];
            s0 += a; q0 += a * a; s1 += bb; q1 += bb * bb;
        }
        psum0[blk * 512 + t] = s0; psum0[blk * 512 + t + 256] = s1;
        psq0 [blk * 512 + t] = q0; psq0 [blk * 512 + t + 256] = q1;
    }
}

// ---------------------------------------------------------------------------
// CSR scan
// ---------------------------------------------------------------------------
__global__ void scan_block_kernel(const int* __restrict__ cnt, int* __restrict__ offs,
                                  int* __restrict__ bsum)
{
    __shared__ int buf[2][256];
    int t = threadIdx.x;
    int i = blockIdx.x * 256 + t;
    int v = cnt[i];
    int p = 0;
    buf[0][t] = v;
    __syncthreads();
    for (int d = 1; d < 256; d <<= 1) {
        int nv = buf[p][t] + ((t >= d) ? buf[p][t - d] : 0);
        buf[p ^ 1][t] = nv;
        p ^= 1;
        __syncthreads();
    }
    int incl = buf[p][t];
    offs[i] = incl - v;
    if (t == 255) bsum[blockIdx.x] = incl;
}

// Fat: add_offs2 (0..255) + bn0 finish (256..383, nblocks=512)
__global__ void add_offs_bnfin_kernel(int* __restrict__ offs, const int* __restrict__ bsum,
                                      int* __restrict__ cursor,
                                      const float* __restrict__ psum0, const float* __restrict__ psq0,
                                      const float* __restrict__ g0, const float* __restrict__ b0,
                                      float* __restrict__ sc0, float* __restrict__ sh0)
{
    int b = blockIdx.x, t = threadIdx.x;
    if (b < 256) {
        __shared__ int buf[2][256];
        int v = bsum[t];
        int p = 0;
        buf[0][t] = v;
        __syncthreads();
        for (int d = 1; d < 256; d <<= 1) {
            int nv = buf[p][t] + ((t >= d) ? buf[p][t - d] : 0);
            buf[p ^ 1][t] = nv;
            p ^= 1;
            __syncthreads();
        }
        int excl = buf[p][b] - bsum[b];
        int i = b * 256 + t;
        int o = offs[i] + excl;
        offs[i] = o;
        cursor[i] = o;
    } else {
        int vb = b - 256;                          // 0..127
        int gw = (vb * 256 + t) >> 6;              // channel 0..511
        int lane = t & 63;
        float s = 0, q = 0;
        for (int i = lane; i < 512; i += 64) {
            s += psum0[(size_t)i * 512 + gw];
            q += psq0 [(size_t)i * 512 + gw];
        }
#pragma unroll
        for (int d = 32; d > 0; d >>= 1) {
            s += __shfl_xor(s, d);
            q += __shfl_xor(q, d);
        }
        if (lane == 0) {
            float m = s * (1.0f / V_PREV);
            float v = q * (1.0f / V_PREV) - m * m;
            float r = rsqrtf(v + 1e-5f);
            float scale = r * g0[gw];
            sc0[gw] = scale;
            sh0[gw] = b0[gw] - m * scale;
        }
    }
}

// bn1 finish (standalone)
__global__ void bn_finish_kernel(const float* __restrict__ psum, const float* __restrict__ psq,
                                 int nblocks, int C, float invN,
                                 const float* __restrict__ g, const float* __restrict__ b,
                                 float* __restrict__ sc, float* __restrict__ sh)
{
    int gw = (blockIdx.x * blockDim.x + threadIdx.x) >> 6;
    int lane = threadIdx.x & 63;
    if (gw >= C) return;
    float s = 0, q = 0;
    for (int i = lane; i < nblocks; i += 64) {
        s += psum[(size_t)i * C + gw];
        q += psq [(size_t)i * C + gw];
    }
#pragma unroll
    for (int d = 32; d > 0; d >>= 1) {
        s += __shfl_xor(s, d);
        q += __shfl_xor(q, d);
    }
    if (lane == 0) {
        float m = s * invN;
        float v = q * invN - m * m;
        float r = rsqrtf(v + 1e-5f);
        float scale = r * g[gw];
        sc[gw] = scale;
        sh[gw] = b[gw] - m * scale;
    }
}

// ---------------------------------------------------------------------------
// Fat: gemm0 256x256-tile (blocks 0..191, XCD-grouped) + fill (192..319)
// gemm0: bx 0: XW = bf16(x)@WresT; 1: XNJ = bn-relu(x)@Uj0; 2: XNI @Ui0
//   grid 192 = 64 M-slabs x 3 N-tiles; 512 thr; acc[4][8]; LDS stride 36.
// fill: 128 blocks x 512 thr x 8 edges: E[p]={s, a, colof[s], a*valof[s]}
// ---------------------------------------------------------------------------
__global__ __launch_bounds__(512, 1)
void fill_gemm0_kernel(const int* __restrict__ src, const int* __restrict__ dst,
                       const float* __restrict__ adjv,
                       const int* __restrict__ colof, const float* __restrict__ valof,
                       int* __restrict__ cursor, int4* __restrict__ E,
                       const float* __restrict__ x,
                       const ushort* __restrict__ WresT, const ushort* __restrict__ W0t,
                       const float* __restrict__ sc0, const float* __restrict__ sh0,
                       ushort* __restrict__ XW, ushort* __restrict__ XNJ,
                       ushort* __restrict__ XNI)
{
    __shared__ ushort As[256 * LSTR];
    __shared__ ushort Bs[256 * LSTR];
    __shared__ float s_sc[512], s_sh[512];

    const int tid = threadIdx.x;
    if (blockIdx.x >= 192) {
        int base = (blockIdx.x - 192) * 4096;
#pragma unroll
        for (int i = 0; i < 8; i++) {
            int e = base + i * 512 + tid;
            int d = dst[e];
            int s = src[e];
            float a = adjv[e];
            int p = atomicAdd(&cursor[d], 1);
            int4 v;
            v.x = s;
            v.y = __float_as_int(a);
            v.z = colof[s];
            v.w = __float_as_int(a * valof[s]);
            E[p] = v;
        }
        return;
    }

    // XCD grouping: slab's 3 N-tiles land on the same XCD
    const int id   = blockIdx.x;
    const int xcd  = id & 7;
    const int rest = id >> 3;          // 0..23
    const int slot = rest / 3;         // 0..7
    const int bx   = rest - slot * 3;  // 0..2
    const int by   = slot * 8 + xcd;   // 0..63
    const int tM   = by * 256;

    const bool bnmode = bx >= 1;
    const ushort* Bt = bnmode ? W0t : WresT;
    const int btrow = bnmode ? (bx - 1) * 256 : 0;
    ushort* Cout = (bx == 0) ? XW : (bx == 1 ? XNJ : XNI);

    s_sc[tid] = sc0[tid]; s_sh[tid] = sh0[tid];
    __syncthreads();

    const int lane = tid & 63;
    const int wave = tid >> 6;
    const int wm = wave >> 1, wn = wave & 1;    // wave tile 64 rows x 128 cols
    const int lr = lane & 15, lg = lane >> 4;

    f32x4 acc[4][8] = {};

    for (int k0 = 0; k0 < 512; k0 += 32) {
        // --- A stage: 256 rows x 4 units, 2 per thread, f32 -> (bn) -> bf16 ---
#pragma unroll
        for (int i = 0; i < 2; i++) {
            int idx = tid + i * 512;
            int row = idx >> 2, u = idx & 3;
            const float* xp = &x[(size_t)(tM + row) * 512 + k0 + u * 8];
            float4 f0 = *(const float4*)(xp);
            float4 f1 = *(const float4*)(xp + 4);
            float vv[8] = { f0.x, f0.y, f0.z, f0.w, f1.x, f1.y, f1.z, f1.w };
            ushort h[8];
            if (bnmode) {
#pragma unroll
                for (int j = 0; j < 8; j++) {
                    int c = k0 + u * 8 + j;
                    h[j] = f2bf(fmaxf(vv[j] * s_sc[c] + s_sh[c], 0.0f));
                }
            } else {
#pragma unroll
                for (int j = 0; j < 8; j++) h[j] = f2bf(vv[j]);
            }
            *(uint4*)&As[row * LSTR + u * 8] = *(uint4*)h;
        }
        // --- B stage: 256 rows x 4 units, 2 per thread ---
#pragma unroll
        for (int i = 0; i < 2; i++) {
            int idx = tid + i * 512;
            int row = idx >> 2, u = idx & 3;
            *(uint4*)&Bs[row * LSTR + u * 8] =
                *(const uint4*)&Bt[(size_t)(btrow + row) * 512 + k0 + u * 8];
        }
        __syncthreads();

        bfrag af[4], bfv[8];
#pragma unroll
        for (int mm = 0; mm < 4; mm++) {
            int row = wm * 64 + mm * 16 + lr;
            af[mm] = *(const bfrag*)&As[row * LSTR + lg * 8];
        }
#pragma unroll
        for (int nn = 0; nn < 8; nn++) {
            int row = wn * 128 + nn * 16 + lr;
            bfv[nn] = *(const bfrag*)&Bs[row * LSTR + lg * 8];
        }
#pragma unroll
        for (int mm = 0; mm < 4; mm++)
#pragma unroll
            for (int nn = 0; nn < 8; nn++)
                acc[mm][nn] = __builtin_amdgcn_mfma_f32_16x16x32_bf16(af[mm], bfv[nn], acc[mm][nn], 0, 0, 0);
        __syncthreads();
    }

#pragma unroll
    for (int mm = 0; mm < 4; mm++)
#pragma unroll
        for (int nn = 0; nn < 8; nn++)
#pragma unroll
            for (int r = 0; r < 4; r++) {
                int row = tM + wm * 64 + mm * 16 + lg * 4 + r;
                int col = wn * 128 + nn * 16 + lr;
                Cout[(size_t)row * 256 + col] = f2bf(acc[mm][nn][r]);
            }
}

// ---------------------------------------------------------------------------
// Gather layer 0, persistent (2048 blocks x 8 iters), 4-wide batched loads.
// sumA computed on the fly; bn1 stats in registers.
// ---------------------------------------------------------------------------
__global__ __launch_bounds__(256)
void gather0_kernel(const int* __restrict__ offs, const int* __restrict__ cnt,
                    const int4* __restrict__ E,
                    const int* __restrict__ colof, const float* __restrict__ valof,
                    const ushort* __restrict__ XNJ, const ushort* __restrict__ XNI,
                    const float* __restrict__ ui_b, const float* __restrict__ uj_b,
                    ushort* __restrict__ X1, float* __restrict__ sumA,
                    float* __restrict__ psum1s, float* __restrict__ psq1s)
{
    __shared__ float redS[4][256];
    __shared__ float redQ[4][256];

    int wave = threadIdx.x >> 6;
    int lane = threadIdx.x & 63;
    int f = lane * 4;
    float ub0 = ui_b[f + 0], ub1 = ui_b[f + 1], ub2 = ui_b[f + 2], ub3 = ui_b[f + 3];
    float jb0 = uj_b[f + 0], jb1 = uj_b[f + 1], jb2 = uj_b[f + 2], jb3 = uj_b[f + 3];
    float ss0 = 0, ss1 = 0, ss2 = 0, ss3 = 0;
    float qq0 = 0, qq1 = 0, qq2 = 0, qq3 = 0;

    for (int it = 0; it < 8; it++) {
        int d = (blockIdx.x * 8 + it) * 4 + wave;
        int c = colof[d];
        float s = valof[d];
        ushort4 u = *(const ushort4*)&XNI[(size_t)c * 256 + f];
        const ushort* up = (const ushort*)&u;
        float a0 = ub0 + s * bf2f(up[0]);
        float a1 = ub1 + s * bf2f(up[1]);
        float a2 = ub2 + s * bf2f(up[2]);
        float a3 = ub3 + s * bf2f(up[3]);
        float sA = 0;

        int st = offs[d], n = cnt[d];
        for (int e0 = 0; e0 < n; e0 += 4) {
            int4 ev0 = E[st + e0];
            int4 ev1 = (e0 + 1 < n) ? E[st + e0 + 1] : make_int4(0, 0, 0, 0);
            int4 ev2 = (e0 + 2 < n) ? E[st + e0 + 2] : make_int4(0, 0, 0, 0);
            int4 ev3 = (e0 + 3 < n) ? E[st + e0 + 3] : make_int4(0, 0, 0, 0);
            float w0 = __int_as_float(ev0.w), w1 = __int_as_float(ev1.w);
            float w2 = __int_as_float(ev2.w), w3 = __int_as_float(ev3.w);
            sA += __int_as_float(ev0.y) + __int_as_float(ev1.y)
                + __int_as_float(ev2.y) + __int_as_float(ev3.y);
            ushort4 v0 = *(const ushort4*)&XNJ[(size_t)ev0.z * 256 + f];
            ushort4 v1 = *(const ushort4*)&XNJ[(size_t)ev1.z * 256 + f];
            ushort4 v2 = *(const ushort4*)&XNJ[(size_t)ev2.z * 256 + f];
            ushort4 v3 = *(const ushort4*)&XNJ[(size_t)ev3.z * 256 + f];
            const ushort* p0 = (const ushort*)&v0;
            const ushort* p1 = (const ushort*)&v1;
            const ushort* p2 = (const ushort*)&v2;
            const ushort* p3 = (const ushort*)&v3;
            a0 += w0 * bf2f(p0[0]) + w1 * bf2f(p1[0]) + w2 * bf2f(p2[0]) + w3 * bf2f(p3[0]);
            a1 += w0 * bf2f(p0[1]) + w1 * bf2f(p1[1]) + w2 * bf2f(p2[1]) + w3 * bf2f(p3[1]);
            a2 += w0 * bf2f(p0[2]) + w1 * bf2f(p1[2]) + w2 * bf2f(p2[2]) + w3 * bf2f(p3[2]);
            a3 += w0 * bf2f(p0[3]) + w1 * bf2f(p1[3]) + w2 * bf2f(p2[3]) + w3 * bf2f(p3[3]);
        }
        a0 += sA * jb0; a1 += sA * jb1; a2 += sA * jb2; a3 += sA * jb3;
        *(ushort4*)&X1[(size_t)d * 256 + f] =
            make_ushort4(f2bf(a0), f2bf(a1), f2bf(a2), f2bf(a3));
        if (lane == 0) sumA[d] = sA;
        ss0 += a0; ss1 += a1; ss2 += a2; ss3 += a3;
        qq0 += a0 * a0; qq1 += a1 * a1; qq2 += a2 * a2; qq3 += a3 * a3;
    }

    redS[wave][f + 0] = ss0; redS[wave][f + 1] = ss1;
    redS[wave][f + 2] = ss2; redS[wave][f + 3] = ss3;
    redQ[wave][f + 0] = qq0; redQ[wave][f + 1] = qq1;
    redQ[wave][f + 2] = qq2; redQ[wave][f + 3] = qq3;
    __syncthreads();
    int t = threadIdx.x;   // channel
    float ssum = redS[0][t] + redS[1][t] + redS[2][t] + redS[3][t];
    float sq   = redQ[0][t] + redQ[1][t] + redQ[2][t] + redQ[3][t];
    int slab = (blockIdx.x & 63) * 256 + t;
    atomicAdd(&psum1s[slab], ssum);
    atomicAdd(&psq1s[slab], sq);
}

// ---------------------------------------------------------------------------
// Gather layer 1 (pre-GEMM, bn1+relu folded), 4-wide:
//   G[d] = sum_e valA * relu(sc1*X1[srcA] + sh1)     (bf16 out)
// ---------------------------------------------------------------------------
__global__ __launch_bounds__(256)
void gather1G_kernel(const int* __restrict__ offs, const int* __restrict__ cnt,
                     const int4* __restrict__ E,
                     const ushort* __restrict__ X1,
                     const float* __restrict__ sc1, const float* __restrict__ sh1,
                     ushort* __restrict__ G)
{
    int d = blockIdx.x * 4 + (threadIdx.x >> 6);
    int f = (threadIdx.x & 63) * 4;
    float4 sc = *(const float4*)&sc1[f];
    float4 sh = *(const float4*)&sh1[f];
    float a0 = 0, a1 = 0, a2 = 0, a3 = 0;

    int st = offs[d], n = cnt[d];
    for (int e0 = 0; e0 < n; e0 += 4) {
        int4 ev0 = E[st + e0];
        int4 ev1 = (e0 + 1 < n) ? E[st + e0 + 1] : make_int4(0, 0, 0, 0);
        int4 ev2 = (e0 + 2 < n) ? E[st + e0 + 2] : make_int4(0, 0, 0, 0);
        int4 ev3 = (e0 + 3 < n) ? E[st + e0 + 3] : make_int4(0, 0, 0, 0);
        float w0 = __int_as_float(ev0.y), w1 = __int_as_float(ev1.y);
        float w2 = __int_as_float(ev2.y), w3 = __int_as_float(ev3.y);
        ushort4 v0 = *(const ushort4*)&X1[(size_t)ev0.x * 256 + f];
        ushort4 v1 = *(const ushort4*)&X1[(size_t)ev1.x * 256 + f];
        ushort4 v2 = *(const ushort4*)&X1[(size_t)ev2.x * 256 + f];
        ushort4 v3 = *(const ushort4*)&X1[(size_t)ev3.x * 256 + f];
        const ushort* p0 = (const ushort*)&v0;
        const ushort* p1 = (const ushort*)&v1;
        const ushort* p2 = (const ushort*)&v2;
        const ushort* p3 = (const ushort*)&v3;
        a0 += w0 * fmaxf(bf2f(p0[0]) * sc.x + sh.x, 0.0f)
            + w1 * fmaxf(bf2f(p1[0]) * sc.x + sh.x, 0.0f)
            + w2 * fmaxf(bf2f(p2[0]) * sc.x + sh.x, 0.0f)
            + w3 * fmaxf(bf2f(p3[0]) * sc.x + sh.x, 0.0f);
        a1 += w0 * fmaxf(bf2f(p0[1]) * sc.y + sh.y, 0.0f)
            + w1 * fmaxf(bf2f(p1[1]) * sc.y + sh.y, 0.0f)
            + w2 * fmaxf(bf2f(p2[1]) * sc.y + sh.y, 0.0f)
            + w3 * fmaxf(bf2f(p3[1]) * sc.y + sh.y, 0.0f);
        a2 += w0 * fmaxf(bf2f(p0[2]) * sc.z + sh.z, 0.0f)
            + w1 * fmaxf(bf2f(p1[2]) * sc.z + sh.z, 0.0f)
            + w2 * fmaxf(bf2f(p2[2]) * sc.z + sh.z, 0.0f)
            + w3 * fmaxf(bf2f(p3[2]) * sc.z + sh.z, 0.0f);
        a3 += w0 * fmaxf(bf2f(p0[3]) * sc.w + sh.w, 0.0f)
            + w1 * fmaxf(bf2f(p1[3]) * sc.w + sh.w, 0.0f)
            + w2 * fmaxf(bf2f(p2[3]) * sc.w + sh.w, 0.0f)
            + w3 * fmaxf(bf2f(p3[3]) * sc.w + sh.w, 0.0f);
    }
    *(ushort4*)&G[(size_t)d * 256 + f] =
        make_ushort4(f2bf(a0), f2bf(a1), f2bf(a2), f2bf(a3));
}

// ---------------------------------------------------------------------------
// GEMM final: out[65536,256] f32 = [relu(bn1(X1)) | G] @ W1cat^T + biases + res
// 256x256 tile, 512 thr, grid 256. LDS stride 36.
// ---------------------------------------------------------------------------
__global__ __launch_bounds__(512, 1)
void gemm_final_kernel(const ushort* __restrict__ X1, const ushort* __restrict__ G,
                       const ushort* __restrict__ W1cat,
                       const float* __restrict__ sc1, const float* __restrict__ sh1,
                       const float* __restrict__ biasUi, const float* __restrict__ uj1_b,
                       const float* __restrict__ sumA,
                       const int* __restrict__ colof, const float* __restrict__ valof,
                       const ushort* __restrict__ XW,
                       float* __restrict__ out)
{
    __shared__ ushort As[256 * LSTR];
    __shared__ ushort Bs[256 * LSTR];
    __shared__ float s_sc[256], s_sh[256];

    const int tid = threadIdx.x;
    const int tM = blockIdx.x * 256;

    if (tid < 256) { s_sc[tid] = sc1[tid]; s_sh[tid] = sh1[tid]; }
    __syncthreads();

    const int lane = tid & 63;
    const int wave = tid >> 6;
    const int wm = wave >> 1, wn = wave & 1;    // wave tile 64 rows x 128 cols
    const int lr = lane & 15, lg = lane >> 4;

    f32x4 acc[4][8] = {};

    for (int k0 = 0; k0 < 512; k0 += 32) {
#pragma unroll
        for (int i = 0; i < 2; i++) {
            int idx = tid + i * 512;
            int row = idx >> 2, u = idx & 3;
            ushort h[8];
            if (k0 < 256) {
                *(uint4*)h = *(const uint4*)&X1[(size_t)(tM + row) * 256 + k0 + u * 8];
#pragma unroll
                for (int j = 0; j < 8; j++) {
                    int c = k0 + u * 8 + j;
                    h[j] = f2bf(fmaxf(bf2f(h[j]) * s_sc[c] + s_sh[c], 0.0f));
                }
            } else {
                *(uint4*)h = *(const uint4*)&G[(size_t)(tM + row) * 256 + (k0 - 256) + u * 8];
            }
            *(uint4*)&As[row * LSTR + u * 8] = *(uint4*)h;
        }
#pragma unroll
        for (int i = 0; i < 2; i++) {
            int idx = tid + i * 512;
            int row = idx >> 2, u = idx & 3;
            *(uint4*)&Bs[row * LSTR + u * 8] =
                *(const uint4*)&W1cat[(size_t)row * 512 + k0 + u * 8];
        }
        __syncthreads();

        bfrag af[4], bfv[8];
#pragma unroll
        for (int mm = 0; mm < 4; mm++) {
            int row = wm * 64 + mm * 16 + lr;
            af[mm] = *(const bfrag*)&As[row * LSTR + lg * 8];
        }
#pragma unroll
        for (int nn = 0; nn < 8; nn++) {
            int row = wn * 128 + nn * 16 + lr;
            bfv[nn] = *(const bfrag*)&Bs[row * LSTR + lg * 8];
        }
#pragma unroll
        for (int mm = 0; mm < 4; mm++)
#pragma unroll
            for (int nn = 0; nn < 8; nn++)
                acc[mm][nn] = __builtin_amdgcn_mfma_f32_16x16x32_bf16(af[mm], bfv[nn], acc[mm][nn], 0, 0, 0);
        __syncthreads();
    }

    float bUi[8], bUj[8];
#pragma unroll
    for (int nn = 0; nn < 8; nn++) {
        int col = wn * 128 + nn * 16 + lr;
        bUi[nn] = biasUi[col];
        bUj[nn] = uj1_b[col];
    }
#pragma unroll
    for (int mm = 0; mm < 4; mm++) {
#pragma unroll
        for (int r = 0; r < 4; r++) {
            int row = tM + wm * 64 + mm * 16 + lg * 4 + r;
            int c = colof[row];
            float s = valof[row];
            float sA = sumA[row];
#pragma unroll
            for (int nn = 0; nn < 8; nn++) {
                int col = wn * 128 + nn * 16 + lr;
                float v = acc[mm][nn][r] + bUi[nn] + sA * bUj[nn]
                        + s * bf2f(XW[(size_t)c * 256 + col]);
                out[(size_t)row * 256 + col] = v;
            }
        }
    }
}

// ---------------------------------------------------------------------------
// Host launcher
// ---------------------------------------------------------------------------
extern "C" void kernel_launch(void* const* d_in, const int* in_sizes, int n_in,
                              void* d_out, int out_size, void* d_ws, size_t ws_size,
                              hipStream_t stream)
{
    const float* x      = (const float*)d_in[0];
    const int*   up_row = (const int*)  d_in[1];
    const int*   up_col = (const int*)  d_in[2];
    const float* up_val = (const float*)d_in[3];
    const int*   e_src  = (const int*)  d_in[4];
    const int*   e_dst  = (const int*)  d_in[5];
    const float* adjv   = (const float*)d_in[6];
    const float* W_res  = (const float*)d_in[7];
    const float* b_res  = (const float*)d_in[8];
    const float* bn0_g  = (const float*)d_in[9];
    const float* bn0_b  = (const float*)d_in[10];
    const float* bn1_g  = (const float*)d_in[11];
    const float* bn1_b  = (const float*)d_in[12];
    const float* Ui0_W  = (const float*)d_in[13];
    const float* Ui0_b  = (const float*)d_in[14];
    const float* Uj0_W  = (const float*)d_in[15];
    const float* Uj0_b  = (const float*)d_in[16];
    const float* Ui1_W  = (const float*)d_in[17];
    const float* Ui1_b  = (const float*)d_in[18];
    const float* Uj1_W  = (const float*)d_in[19];
    const float* Uj1_b  = (const float*)d_in[20];

    float* out = (float*)d_out;

    // ---- workspace layout ----
    char* ws = (char*)d_ws;
    size_t off = 0;
    auto alloc = [&](size_t bytes) -> char* {
        char* p = ws + off;
        off = (off + bytes + 255) & ~(size_t)255;
        return p;
    };
    ushort* XW    = (ushort*)alloc((size_t)V_PREV * F_OUT * 2);   // 8.4 MB
    ushort* XNJ   = (ushort*)alloc((size_t)V_PREV * F_OUT * 2);   // 8.4 MB
    ushort* XNI   = (ushort*)alloc((size_t)V_PREV * F_OUT * 2);   // 8.4 MB
    ushort* X1    = (ushort*)alloc((size_t)V_NEXT * F_OUT * 2);   // 33.6 MB
    ushort* G     = (ushort*)alloc((size_t)V_NEXT * F_OUT * 2);   // 33.6 MB
    // --- zeroed region (memsetAsync): cnt, psum1s, psq1s = 98304 ints ---
    int*    cnt   = (int*)   alloc(V_NEXT * 4);                   // 256 KB
    float*  psum1s= (float*) alloc(64 * 256 * 4);                 // 64 KB
    float*  psq1s = (float*) alloc(64 * 256 * 4);                 // 64 KB
    float*  sumA  = (float*) alloc(V_NEXT * 4);
    int*    offs  = (int*)   alloc(V_NEXT * 4);
    int*    cursor= (int*)   alloc(V_NEXT * 4);
    int*    bsum  = (int*)   alloc(256 * 4);
    int4*   E     = (int4*)  alloc((size_t)N_EDGE * 16);          // 8.4 MB
    int*    colof = (int*)   alloc(V_NEXT * 4);
    float*  valof = (float*) alloc(V_NEXT * 4);
    ushort* WresT = (ushort*)alloc(256 * 512 * 2);
    ushort* W0t   = (ushort*)alloc(512 * 512 * 2);
    ushort* W1cat = (ushort*)alloc(256 * 512 * 2);
    float*  biasUi= (float*) alloc(256 * 4);
    float*  psum0 = (float*) alloc(512 * 512 * 4);                // 1 MB
    float*  psq0  = (float*) alloc(512 * 512 * 4);                // 1 MB
    float*  sc0   = (float*) alloc(512 * 4);
    float*  sh0   = (float*) alloc(512 * 4);
    float*  sc1   = (float*) alloc(256 * 4);
    float*  sh1   = (float*) alloc(256 * 4);
    (void)ws_size; (void)in_sizes; (void)n_in; (void)out_size;

    // ---- K0: zero cnt + psum1s + psq1s (contiguous) ----
    hipMemsetAsync(cnt, 0, (size_t)98304 * 4, stream);

    // ---- K1: mega prep: weights + up-invert + hist + bn0 partials ----
    mega_prep_kernel<<<3840, 256, 0, stream>>>(W_res, Ui0_W, Uj0_W, Ui1_W, Uj1_W,
                                               Ui1_b, b_res,
                                               up_row, up_col, up_val,
                                               e_dst, x,
                                               WresT, W0t, W1cat, biasUi,
                                               colof, valof, cnt, psum0, psq0);

    // ---- K2: block scan ----
    scan_block_kernel<<<256, 256, 0, stream>>>(cnt, offs, bsum);

    // ---- K3: offset add + bn0 finish ----
    add_offs_bnfin_kernel<<<384, 256, 0, stream>>>(offs, bsum, cursor,
                                                   psum0, psq0, bn0_g, bn0_b, sc0, sh0);

    // ---- K4: gemm0 (256-tile, blocks 0..191) + edge fill (192..319) ----
    fill_gemm0_kernel<<<320, 512, 0, stream>>>(e_src, e_dst, adjv, colof, valof,
                                               cursor, E,
                                               x, WresT, W0t, sc0, sh0,
                                               XW, XNJ, XNI);

    // ---- K5: ECC layer 0 aggregation + sumA + bn1 stats (persistent) ----
    gather0_kernel<<<2048, 256, 0, stream>>>(offs, cnt, E, colof, valof,
                                             XNJ, XNI, Ui0_b, Uj0_b,
                                             X1, sumA, psum1s, psq1s);

    // ---- K6: bn1 finish ----
    bn_finish_kernel<<<64, 256, 0, stream>>>(psum1s, psq1s, 64, 256, 1.0f / V_NEXT,
                                             bn1_g, bn1_b, sc1, sh1);

    // ---- K7: ECC layer 1 aggregation (commuted) ----
    gather1G_kernel<<<V_NEXT / 4, 256, 0, stream>>>(offs, cnt, E, X1, sc1, sh1, G);

    // ---- K8: final GEMM: out = [H1|G] @ W1cat + biases + residual ----
    gemm_final_kernel<<<256, 512, 0, stream>>>(X1, G, W1cat, sc1, sh1,
                                               biasUi, Uj1_b, sumA,
                                               colof, valof, XW, out);
}

// Round 16
// 239.743 us; speedup vs baseline: 1.0030x; 1.0030x over previous
//
#include <hip/hip_runtime.h>

// ---------------------------------------------------------------------------
// Problem constants
// ---------------------------------------------------------------------------
#define V_PREV 16384
#define V_NEXT 65536
#define F_IN   512
#define F_OUT  256
#define NNZ_UP 65536
#define N_EDGE 524288

using f32x4 = __attribute__((ext_vector_type(4))) float;
using bfrag = __attribute__((ext_vector_type(8))) short;   // 8 x bf16

#define LSTR 36   // LDS row stride in shorts: bank base 18*row mod 32 -> <=2-way

__device__ __forceinline__ ushort f2bf(float f) {
    union { float f; unsigned u; } v; v.f = f;
    unsigned r = (v.u + 0x7FFFu + ((v.u >> 16) & 1u)) >> 16;
    return (ushort)r;
}
__device__ __forceinline__ float bf2f(ushort h) {
    union { unsigned u; float f; } v; v.u = ((unsigned)h) << 16; return v.f;
}

// ---------------------------------------------------------------------------
// Mega K1: weight prep (0..1023) + invert_up (1024..1279)
//        + hist cnt (1280..3327) + bn0_part + XBF=bf16(x) (3328..3839)
// (cnt/psum1s/psq1s zeroed by memsetAsync BEFORE this kernel)
// ---------------------------------------------------------------------------
__global__ void mega_prep_kernel(const float* __restrict__ Wres,
                                 const float* __restrict__ Ui0W, const float* __restrict__ Uj0W,
                                 const float* __restrict__ Ui1W, const float* __restrict__ Uj1W,
                                 const float* __restrict__ Ui1b, const float* __restrict__ bres,
                                 const int* __restrict__ up_row, const int* __restrict__ up_col,
                                 const float* __restrict__ up_val,
                                 const int* __restrict__ dst,
                                 const float* __restrict__ x,
                                 ushort* __restrict__ WresT, ushort* __restrict__ W0t,
                                 ushort* __restrict__ W1cat, float* __restrict__ biasUi,
                                 int* __restrict__ colof, float* __restrict__ valof,
                                 int* __restrict__ cnt,
                                 float* __restrict__ psum0, float* __restrict__ psq0,
                                 ushort* __restrict__ XBF)
{
    int b = blockIdx.x, t = threadIdx.x;
    if (b < 1024) {
        int i = b * 256 + t;                      // 0 .. 262143
        if (i < 256 * 512) {
            int n = i / 512, k = i % 512;
            WresT[i] = f2bf(Wres[k * 256 + n]);
            W1cat[i] = f2bf(k < 256 ? Ui1W[k * 256 + n] : Uj1W[(k - 256) * 256 + n]);
        }
        {
            int n = i / 512, k = i % 512;
            W0t[i] = f2bf(n < 256 ? Uj0W[k * 256 + n] : Ui0W[k * 256 + (n - 256)]);
        }
        if (i < 256) biasUi[i] = Ui1b[i] + bres[i];
    } else if (b < 1280) {
        int k = (b - 1024) * 256 + t;             // 0 .. 65535
        int r = up_row[k];
        colof[r] = up_col[k];
        valof[r] = up_val[k];
    } else if (b < 3328) {
        int e = (b - 1280) * 256 + t;             // 0 .. 524287
        atomicAdd(&cnt[dst[e]], 1);
    } else {
        int blk = b - 3328;                        // 0..511, 32 rows each
        float s0 = 0, s1 = 0, q0 = 0, q1 = 0;
        for (int r = 0; r < 32; r++) {
            size_t base = ((size_t)blk * 32 + r) * 512;
            float a = x[base + t], bb = x[base + t + 256];
            s0 += a; q0 += a * a; s1 += bb; q1 += bb * bb;
            XBF[base + t]       = f2bf(a);
            XBF[base + t + 256] = f2bf(bb);
        }
        psum0[blk * 512 + t] = s0; psum0[blk * 512 + t + 256] = s1;
        psq0 [blk * 512 + t] = q0; psq0 [blk * 512 + t + 256] = q1;
    }
}

// ---------------------------------------------------------------------------
// CSR scan
// ---------------------------------------------------------------------------
__global__ void scan_block_kernel(const int* __restrict__ cnt, int* __restrict__ offs,
                                  int* __restrict__ bsum)
{
    __shared__ int buf[2][256];
    int t = threadIdx.x;
    int i = blockIdx.x * 256 + t;
    int v = cnt[i];
    int p = 0;
    buf[0][t] = v;
    __syncthreads();
    for (int d = 1; d < 256; d <<= 1) {
        int nv = buf[p][t] + ((t >= d) ? buf[p][t - d] : 0);
        buf[p ^ 1][t] = nv;
        p ^= 1;
        __syncthreads();
    }
    int incl = buf[p][t];
    offs[i] = incl - v;
    if (t == 255) bsum[blockIdx.x] = incl;
}

// Fat: add_offs2 (0..255) + bn0 finish (256..383, nblocks=512)
__global__ void add_offs_bnfin_kernel(int* __restrict__ offs, const int* __restrict__ bsum,
                                      int* __restrict__ cursor,
                                      const float* __restrict__ psum0, const float* __restrict__ psq0,
                                      const float* __restrict__ g0, const float* __restrict__ b0,
                                      float* __restrict__ sc0, float* __restrict__ sh0)
{
    int b = blockIdx.x, t = threadIdx.x;
    if (b < 256) {
        __shared__ int buf[2][256];
        int v = bsum[t];
        int p = 0;
        buf[0][t] = v;
        __syncthreads();
        for (int d = 1; d < 256; d <<= 1) {
            int nv = buf[p][t] + ((t >= d) ? buf[p][t - d] : 0);
            buf[p ^ 1][t] = nv;
            p ^= 1;
            __syncthreads();
        }
        int excl = buf[p][b] - bsum[b];
        int i = b * 256 + t;
        int o = offs[i] + excl;
        offs[i] = o;
        cursor[i] = o;
    } else {
        int vb = b - 256;                          // 0..127
        int gw = (vb * 256 + t) >> 6;              // channel 0..511
        int lane = t & 63;
        float s = 0, q = 0;
        for (int i = lane; i < 512; i += 64) {
            s += psum0[(size_t)i * 512 + gw];
            q += psq0 [(size_t)i * 512 + gw];
        }
#pragma unroll
        for (int d = 32; d > 0; d >>= 1) {
            s += __shfl_xor(s, d);
            q += __shfl_xor(q, d);
        }
        if (lane == 0) {
            float m = s * (1.0f / V_PREV);
            float v = q * (1.0f / V_PREV) - m * m;
            float r = rsqrtf(v + 1e-5f);
            float scale = r * g0[gw];
            sc0[gw] = scale;
            sh0[gw] = b0[gw] - m * scale;
        }
    }
}

// bn1 finish (standalone)
__global__ void bn_finish_kernel(const float* __restrict__ psum, const float* __restrict__ psq,
                                 int nblocks, int C, float invN,
                                 const float* __restrict__ g, const float* __restrict__ b,
                                 float* __restrict__ sc, float* __restrict__ sh)
{
    int gw = (blockIdx.x * blockDim.x + threadIdx.x) >> 6;
    int lane = threadIdx.x & 63;
    if (gw >= C) return;
    float s = 0, q = 0;
    for (int i = lane; i < nblocks; i += 64) {
        s += psum[(size_t)i * C + gw];
        q += psq [(size_t)i * C + gw];
    }
#pragma unroll
    for (int d = 32; d > 0; d >>= 1) {
        s += __shfl_xor(s, d);
        q += __shfl_xor(q, d);
    }
    if (lane == 0) {
        float m = s * invN;
        float v = q * invN - m * m;
        float r = rsqrtf(v + 1e-5f);
        float scale = r * g[gw];
        sc[gw] = scale;
        sh[gw] = b[gw] - m * scale;
    }
}

// ---------------------------------------------------------------------------
// Fat: fill (0..2047) + gemm0 (2048..2815, XCD-grouped)  [R14 structure]
// fill: E[p] = {srcA, valA, src0=colof[s], val0=a*valof[s]}  (one 16B store)
// gemm0: A = XBF (bf16 copy of x); bx 0,1: XW = XBF@WresT;
//        2,3: XNJ = bn-relu(XBF)@Uj0; 4,5: XNI @Ui0
// LDS stride 36 shorts: <=2-way banks on reads and writes.
// ---------------------------------------------------------------------------
__global__ __launch_bounds__(256)
void fill_gemm0_kernel(const int* __restrict__ src, const int* __restrict__ dst,
                       const float* __restrict__ adjv,
                       const int* __restrict__ colof, const float* __restrict__ valof,
                       int* __restrict__ cursor, int4* __restrict__ E,
                       const ushort* __restrict__ XBF,
                       const ushort* __restrict__ WresT, const ushort* __restrict__ W0t,
                       const float* __restrict__ sc0, const float* __restrict__ sh0,
                       ushort* __restrict__ XW, ushort* __restrict__ XNJ,
                       ushort* __restrict__ XNI)
{
    __shared__ ushort As[128 * LSTR];
    __shared__ ushort Bs[128 * LSTR];
    __shared__ float s_sc[512], s_sh[512];

    const int tid = threadIdx.x;
    if (blockIdx.x < 2048) {
        int e = blockIdx.x * 256 + tid;
        int d = dst[e];
        int s = src[e];
        float a = adjv[e];
        int p = atomicAdd(&cursor[d], 1);
        int4 v;
        v.x = s;
        v.y = __float_as_int(a);
        v.z = colof[s];
        v.w = __float_as_int(a * valof[s]);
        E[p] = v;
        return;
    }

    const int id   = blockIdx.x - 2048;        // 0..767
    const int xcd  = id & 7;
    const int rest = id >> 3;
    const int slot = rest / 6;
    const int bx   = rest - slot * 6;
    const int by   = slot * 8 + xcd;

    const bool bnmode = bx >= 2;
    const ushort* Bt = bnmode ? W0t : WresT;
    const int btrow = bnmode ? (bx - 2) * 128 : bx * 128;
    ushort* Cout = (bx < 2) ? XW : (bx < 4 ? XNJ : XNI);
    const int colbase = (bx & 1) * 128;
    const int tM = by * 128;

    for (int i = tid; i < 512; i += 256) { s_sc[i] = sc0[i]; s_sh[i] = sh0[i]; }
    __syncthreads();

    const int lane = tid & 63;
    const int wave = tid >> 6;
    const int wm = wave >> 1, wn = wave & 1;
    const int lr = lane & 15, lg = lane >> 4;

    const int ra = tid >> 1;
    const int ua = (tid & 1) * 2;
    const int rb = tid >> 2;
    const int ub = tid & 3;

    f32x4 acc[4][4] = {};

    for (int k0 = 0; k0 < 512; k0 += 32) {
        // --- A stage: 2x 8 bf16 units, optional bn+relu ---
        ushort h0[8], h1[8];
        *(uint4*)h0 = *(const uint4*)&XBF[(size_t)(tM + ra) * 512 + k0 + ua * 8];
        *(uint4*)h1 = *(const uint4*)&XBF[(size_t)(tM + ra) * 512 + k0 + (ua + 1) * 8];
        if (bnmode) {
#pragma unroll
            for (int j = 0; j < 8; j++) {
                int c0 = k0 + ua * 8 + j;
                int c1 = c0 + 8;
                h0[j] = f2bf(fmaxf(bf2f(h0[j]) * s_sc[c0] + s_sh[c0], 0.0f));
                h1[j] = f2bf(fmaxf(bf2f(h1[j]) * s_sc[c1] + s_sh[c1], 0.0f));
            }
        }
        *(uint4*)&As[ra * LSTR + ua * 8]       = *(uint4*)h0;
        *(uint4*)&As[ra * LSTR + (ua + 1) * 8] = *(uint4*)h1;

#pragma unroll
        for (int i = 0; i < 2; i++) {
            int row = rb + i * 64;
            *(uint4*)&Bs[row * LSTR + ub * 8] =
                *(const uint4*)&Bt[(size_t)(btrow + row) * 512 + k0 + ub * 8];
        }
        __syncthreads();

        bfrag af[4], bfv[4];
#pragma unroll
        for (int mm = 0; mm < 4; mm++) {
            int row = wm * 64 + mm * 16 + lr;
            af[mm] = *(const bfrag*)&As[row * LSTR + lg * 8];
        }
#pragma unroll
        for (int nn = 0; nn < 4; nn++) {
            int row = wn * 64 + nn * 16 + lr;
            bfv[nn] = *(const bfrag*)&Bs[row * LSTR + lg * 8];
        }
#pragma unroll
        for (int mm = 0; mm < 4; mm++)
#pragma unroll
            for (int nn = 0; nn < 4; nn++)
                acc[mm][nn] = __builtin_amdgcn_mfma_f32_16x16x32_bf16(af[mm], bfv[nn], acc[mm][nn], 0, 0, 0);
        __syncthreads();
    }

#pragma unroll
    for (int mm = 0; mm < 4; mm++)
#pragma unroll
        for (int nn = 0; nn < 4; nn++)
#pragma unroll
            for (int r = 0; r < 4; r++) {
                int row = tM + wm * 64 + mm * 16 + lg * 4 + r;
                int col = colbase + wn * 64 + nn * 16 + lr;
                Cout[(size_t)row * 256 + col] = f2bf(acc[mm][nn][r]);
            }
}

// ---------------------------------------------------------------------------
// Gather layer 0, persistent (2048 blocks x 8 iters), 4-wide batched loads.
// sumA computed on the fly; bn1 stats in registers.
// ---------------------------------------------------------------------------
__global__ __launch_bounds__(256)
void gather0_kernel(const int* __restrict__ offs, const int* __restrict__ cnt,
                    const int4* __restrict__ E,
                    const int* __restrict__ colof, const float* __restrict__ valof,
                    const ushort* __restrict__ XNJ, const ushort* __restrict__ XNI,
                    const float* __restrict__ ui_b, const float* __restrict__ uj_b,
                    ushort* __restrict__ X1, float* __restrict__ sumA,
                    float* __restrict__ psum1s, float* __restrict__ psq1s)
{
    __shared__ float redS[4][256];
    __shared__ float redQ[4][256];

    int wave = threadIdx.x >> 6;
    int lane = threadIdx.x & 63;
    int f = lane * 4;
    float ub0 = ui_b[f + 0], ub1 = ui_b[f + 1], ub2 = ui_b[f + 2], ub3 = ui_b[f + 3];
    float jb0 = uj_b[f + 0], jb1 = uj_b[f + 1], jb2 = uj_b[f + 2], jb3 = uj_b[f + 3];
    float ss0 = 0, ss1 = 0, ss2 = 0, ss3 = 0;
    float qq0 = 0, qq1 = 0, qq2 = 0, qq3 = 0;

    for (int it = 0; it < 8; it++) {
        int d = (blockIdx.x * 8 + it) * 4 + wave;
        int c = colof[d];
        float s = valof[d];
        ushort4 u = *(const ushort4*)&XNI[(size_t)c * 256 + f];
        const ushort* up = (const ushort*)&u;
        float a0 = ub0 + s * bf2f(up[0]);
        float a1 = ub1 + s * bf2f(up[1]);
        float a2 = ub2 + s * bf2f(up[2]);
        float a3 = ub3 + s * bf2f(up[3]);
        float sA = 0;

        int st = offs[d], n = cnt[d];
        for (int e0 = 0; e0 < n; e0 += 4) {
            int4 ev0 = E[st + e0];
            int4 ev1 = (e0 + 1 < n) ? E[st + e0 + 1] : make_int4(0, 0, 0, 0);
            int4 ev2 = (e0 + 2 < n) ? E[st + e0 + 2] : make_int4(0, 0, 0, 0);
            int4 ev3 = (e0 + 3 < n) ? E[st + e0 + 3] : make_int4(0, 0, 0, 0);
            float w0 = __int_as_float(ev0.w), w1 = __int_as_float(ev1.w);
            float w2 = __int_as_float(ev2.w), w3 = __int_as_float(ev3.w);
            sA += __int_as_float(ev0.y) + __int_as_float(ev1.y)
                + __int_as_float(ev2.y) + __int_as_float(ev3.y);
            ushort4 v0 = *(const ushort4*)&XNJ[(size_t)ev0.z * 256 + f];
            ushort4 v1 = *(const ushort4*)&XNJ[(size_t)ev1.z * 256 + f];
            ushort4 v2 = *(const ushort4*)&XNJ[(size_t)ev2.z * 256 + f];
            ushort4 v3 = *(const ushort4*)&XNJ[(size_t)ev3.z * 256 + f];
            const ushort* p0 = (const ushort*)&v0;
            const ushort* p1 = (const ushort*)&v1;
            const ushort* p2 = (const ushort*)&v2;
            const ushort* p3 = (const ushort*)&v3;
            a0 += w0 * bf2f(p0[0]) + w1 * bf2f(p1[0]) + w2 * bf2f(p2[0]) + w3 * bf2f(p3[0]);
            a1 += w0 * bf2f(p0[1]) + w1 * bf2f(p1[1]) + w2 * bf2f(p2[1]) + w3 * bf2f(p3[1]);
            a2 += w0 * bf2f(p0[2]) + w1 * bf2f(p1[2]) + w2 * bf2f(p2[2]) + w3 * bf2f(p3[2]);
            a3 += w0 * bf2f(p0[3]) + w1 * bf2f(p1[3]) + w2 * bf2f(p2[3]) + w3 * bf2f(p3[3]);
        }
        a0 += sA * jb0; a1 += sA * jb1; a2 += sA * jb2; a3 += sA * jb3;
        *(ushort4*)&X1[(size_t)d * 256 + f] =
            make_ushort4(f2bf(a0), f2bf(a1), f2bf(a2), f2bf(a3));
        if (lane == 0) sumA[d] = sA;
        ss0 += a0; ss1 += a1; ss2 += a2; ss3 += a3;
        qq0 += a0 * a0; qq1 += a1 * a1; qq2 += a2 * a2; qq3 += a3 * a3;
    }

    redS[wave][f + 0] = ss0; redS[wave][f + 1] = ss1;
    redS[wave][f + 2] = ss2; redS[wave][f + 3] = ss3;
    redQ[wave][f + 0] = qq0; redQ[wave][f + 1] = qq1;
    redQ[wave][f + 2] = qq2; redQ[wave][f + 3] = qq3;
    __syncthreads();
    int t = threadIdx.x;   // channel
    float ssum = redS[0][t] + redS[1][t] + redS[2][t] + redS[3][t];
    float sq   = redQ[0][t] + redQ[1][t] + redQ[2][t] + redQ[3][t];
    int slab = (blockIdx.x & 63) * 256 + t;
    atomicAdd(&psum1s[slab], ssum);
    atomicAdd(&psq1s[slab], sq);
}

// ---------------------------------------------------------------------------
// Gather layer 1 (pre-GEMM, bn1+relu folded), 4-wide:
//   G[d] = sum_e valA * relu(sc1*X1[srcA] + sh1)     (bf16 out)
// ---------------------------------------------------------------------------
__global__ __launch_bounds__(256)
void gather1G_kernel(const int* __restrict__ offs, const int* __restrict__ cnt,
                     const int4* __restrict__ E,
                     const ushort* __restrict__ X1,
                     const float* __restrict__ sc1, const float* __restrict__ sh1,
                     ushort* __restrict__ G)
{
    int d = blockIdx.x * 4 + (threadIdx.x >> 6);
    int f = (threadIdx.x & 63) * 4;
    float4 sc = *(const float4*)&sc1[f];
    float4 sh = *(const float4*)&sh1[f];
    float a0 = 0, a1 = 0, a2 = 0, a3 = 0;

    int st = offs[d], n = cnt[d];
    for (int e0 = 0; e0 < n; e0 += 4) {
        int4 ev0 = E[st + e0];
        int4 ev1 = (e0 + 1 < n) ? E[st + e0 + 1] : make_int4(0, 0, 0, 0);
        int4 ev2 = (e0 + 2 < n) ? E[st + e0 + 2] : make_int4(0, 0, 0, 0);
        int4 ev3 = (e0 + 3 < n) ? E[st + e0 + 3] : make_int4(0, 0, 0, 0);
        float w0 = __int_as_float(ev0.y), w1 = __int_as_float(ev1.y);
        float w2 = __int_as_float(ev2.y), w3 = __int_as_float(ev3.y);
        ushort4 v0 = *(const ushort4*)&X1[(size_t)ev0.x * 256 + f];
        ushort4 v1 = *(const ushort4*)&X1[(size_t)ev1.x * 256 + f];
        ushort4 v2 = *(const ushort4*)&X1[(size_t)ev2.x * 256 + f];
        ushort4 v3 = *(const ushort4*)&X1[(size_t)ev3.x * 256 + f];
        const ushort* p0 = (const ushort*)&v0;
        const ushort* p1 = (const ushort*)&v1;
        const ushort* p2 = (const ushort*)&v2;
        const ushort* p3 = (const ushort*)&v3;
        a0 += w0 * fmaxf(bf2f(p0[0]) * sc.x + sh.x, 0.0f)
            + w1 * fmaxf(bf2f(p1[0]) * sc.x + sh.x, 0.0f)
            + w2 * fmaxf(bf2f(p2[0]) * sc.x + sh.x, 0.0f)
            + w3 * fmaxf(bf2f(p3[0]) * sc.x + sh.x, 0.0f);
        a1 += w0 * fmaxf(bf2f(p0[1]) * sc.y + sh.y, 0.0f)
            + w1 * fmaxf(bf2f(p1[1]) * sc.y + sh.y, 0.0f)
            + w2 * fmaxf(bf2f(p2[1]) * sc.y + sh.y, 0.0f)
            + w3 * fmaxf(bf2f(p3[1]) * sc.y + sh.y, 0.0f);
        a2 += w0 * fmaxf(bf2f(p0[2]) * sc.z + sh.z, 0.0f)
            + w1 * fmaxf(bf2f(p1[2]) * sc.z + sh.z, 0.0f)
            + w2 * fmaxf(bf2f(p2[2]) * sc.z + sh.z, 0.0f)
            + w3 * fmaxf(bf2f(p3[2]) * sc.z + sh.z, 0.0f);
        a3 += w0 * fmaxf(bf2f(p0[3]) * sc.w + sh.w, 0.0f)
            + w1 * fmaxf(bf2f(p1[3]) * sc.w + sh.w, 0.0f)
            + w2 * fmaxf(bf2f(p2[3]) * sc.w + sh.w, 0.0f)
            + w3 * fmaxf(bf2f(p3[3]) * sc.w + sh.w, 0.0f);
    }
    *(ushort4*)&G[(size_t)d * 256 + f] =
        make_ushort4(f2bf(a0), f2bf(a1), f2bf(a2), f2bf(a3));
}

// ---------------------------------------------------------------------------
// GEMM final: out[65536,256] f32 = [relu(bn1(X1)) | G] @ W1cat^T + biases + res
// 256x256 tile, 512 thr, grid 256. LDS stride 36.
// ---------------------------------------------------------------------------
__global__ __launch_bounds__(512, 1)
void gemm_final_kernel(const ushort* __restrict__ X1, const ushort* __restrict__ G,
                       const ushort* __restrict__ W1cat,
                       const float* __restrict__ sc1, const float* __restrict__ sh1,
                       const float* __restrict__ biasUi, const float* __restrict__ uj1_b,
                       const float* __restrict__ sumA,
                       const int* __restrict__ colof, const float* __restrict__ valof,
                       const ushort* __restrict__ XW,
                       float* __restrict__ out)
{
    __shared__ ushort As[256 * LSTR];
    __shared__ ushort Bs[256 * LSTR];
    __shared__ float s_sc[256], s_sh[256];

    const int tid = threadIdx.x;
    const int tM = blockIdx.x * 256;

    if (tid < 256) { s_sc[tid] = sc1[tid]; s_sh[tid] = sh1[tid]; }
    __syncthreads();

    const int lane = tid & 63;
    const int wave = tid >> 6;
    const int wm = wave >> 1, wn = wave & 1;    // wave tile 64 rows x 128 cols
    const int lr = lane & 15, lg = lane >> 4;

    f32x4 acc[4][8] = {};

    for (int k0 = 0; k0 < 512; k0 += 32) {
#pragma unroll
        for (int i = 0; i < 2; i++) {
            int idx = tid + i * 512;
            int row = idx >> 2, u = idx & 3;
            ushort h[8];
            if (k0 < 256) {
                *(uint4*)h = *(const uint4*)&X1[(size_t)(tM + row) * 256 + k0 + u * 8];
#pragma unroll
                for (int j = 0; j < 8; j++) {
                    int c = k0 + u * 8 + j;
                    h[j] = f2bf(fmaxf(bf2f(h[j]) * s_sc[c] + s_sh[c], 0.0f));
                }
            } else {
                *(uint4*)h = *(const uint4*)&G[(size_t)(tM + row) * 256 + (k0 - 256) + u * 8];
            }
            *(uint4*)&As[row * LSTR + u * 8] = *(uint4*)h;
        }
#pragma unroll
        for (int i = 0; i < 2; i++) {
            int idx = tid + i * 512;
            int row = idx >> 2, u = idx & 3;
            *(uint4*)&Bs[row * LSTR + u * 8] =
                *(const uint4*)&W1cat[(size_t)row * 512 + k0 + u * 8];
        }
        __syncthreads();

        bfrag af[4], bfv[8];
#pragma unroll
        for (int mm = 0; mm < 4; mm++) {
            int row = wm * 64 + mm * 16 + lr;
            af[mm] = *(const bfrag*)&As[row * LSTR + lg * 8];
        }
#pragma unroll
        for (int nn = 0; nn < 8; nn++) {
            int row = wn * 128 + nn * 16 + lr;
            bfv[nn] = *(const bfrag*)&Bs[row * LSTR + lg * 8];
        }
#pragma unroll
        for (int mm = 0; mm < 4; mm++)
#pragma unroll
            for (int nn = 0; nn < 8; nn++)
                acc[mm][nn] = __builtin_amdgcn_mfma_f32_16x16x32_bf16(af[mm], bfv[nn], acc[mm][nn], 0, 0, 0);
        __syncthreads();
    }

    float bUi[8], bUj[8];
#pragma unroll
    for (int nn = 0; nn < 8; nn++) {
        int col = wn * 128 + nn * 16 + lr;
        bUi[nn] = biasUi[col];
        bUj[nn] = uj1_b[col];
    }
#pragma unroll
    for (int mm = 0; mm < 4; mm++) {
#pragma unroll
        for (int r = 0; r < 4; r++) {
            int row = tM + wm * 64 + mm * 16 + lg * 4 + r;
            int c = colof[row];
            float s = valof[row];
            float sA = sumA[row];
#pragma unroll
            for (int nn = 0; nn < 8; nn++) {
                int col = wn * 128 + nn * 16 + lr;
                float v = acc[mm][nn][r] + bUi[nn] + sA * bUj[nn]
                        + s * bf2f(XW[(size_t)c * 256 + col]);
                out[(size_t)row * 256 + col] = v;
            }
        }
    }
}

// ---------------------------------------------------------------------------
// Host launcher
// ---------------------------------------------------------------------------
extern "C" void kernel_launch(void* const* d_in, const int* in_sizes, int n_in,
                              void* d_out, int out_size, void* d_ws, size_t ws_size,
                              hipStream_t stream)
{
    const float* x      = (const float*)d_in[0];
    const int*   up_row = (const int*)  d_in[1];
    const int*   up_col = (const int*)  d_in[2];
    const float* up_val = (const float*)d_in[3];
    const int*   e_src  = (const int*)  d_in[4];
    const int*   e_dst  = (const int*)  d_in[5];
    const float* adjv   = (const float*)d_in[6];
    const float* W_res  = (const float*)d_in[7];
    const float* b_res  = (const float*)d_in[8];
    const float* bn0_g  = (const float*)d_in[9];
    const float* bn0_b  = (const float*)d_in[10];
    const float* bn1_g  = (const float*)d_in[11];
    const float* bn1_b  = (const float*)d_in[12];
    const float* Ui0_W  = (const float*)d_in[13];
    const float* Ui0_b  = (const float*)d_in[14];
    const float* Uj0_W  = (const float*)d_in[15];
    const float* Uj0_b  = (const float*)d_in[16];
    const float* Ui1_W  = (const float*)d_in[17];
    const float* Ui1_b  = (const float*)d_in[18];
    const float* Uj1_W  = (const float*)d_in[19];
    const float* Uj1_b  = (const float*)d_in[20];

    float* out = (float*)d_out;

    // ---- workspace layout ----
    char* ws = (char*)d_ws;
    size_t off = 0;
    auto alloc = [&](size_t bytes) -> char* {
        char* p = ws + off;
        off = (off + bytes + 255) & ~(size_t)255;
        return p;
    };
    ushort* XW    = (ushort*)alloc((size_t)V_PREV * F_OUT * 2);   // 8.4 MB
    ushort* XNJ   = (ushort*)alloc((size_t)V_PREV * F_OUT * 2);   // 8.4 MB
    ushort* XNI   = (ushort*)alloc((size_t)V_PREV * F_OUT * 2);   // 8.4 MB
    ushort* XBF   = (ushort*)alloc((size_t)V_PREV * F_IN * 2);    // 16.8 MB
    ushort* X1    = (ushort*)alloc((size_t)V_NEXT * F_OUT * 2);   // 33.6 MB
    ushort* G     = (ushort*)alloc((size_t)V_NEXT * F_OUT * 2);   // 33.6 MB
    // --- zeroed region (memsetAsync): cnt, psum1s, psq1s = 98304 ints ---
    int*    cnt   = (int*)   alloc(V_NEXT * 4);                   // 256 KB
    float*  psum1s= (float*) alloc(64 * 256 * 4);                 // 64 KB
    float*  psq1s = (float*) alloc(64 * 256 * 4);                 // 64 KB
    float*  sumA  = (float*) alloc(V_NEXT * 4);
    int*    offs  = (int*)   alloc(V_NEXT * 4);
    int*    cursor= (int*)   alloc(V_NEXT * 4);
    int*    bsum  = (int*)   alloc(256 * 4);
    int4*   E     = (int4*)  alloc((size_t)N_EDGE * 16);          // 8.4 MB
    int*    colof = (int*)   alloc(V_NEXT * 4);
    float*  valof = (float*) alloc(V_NEXT * 4);
    ushort* WresT = (ushort*)alloc(256 * 512 * 2);
    ushort* W0t   = (ushort*)alloc(512 * 512 * 2);
    ushort* W1cat = (ushort*)alloc(256 * 512 * 2);
    float*  biasUi= (float*) alloc(256 * 4);
    float*  psum0 = (float*) alloc(512 * 512 * 4);                // 1 MB
    float*  psq0  = (float*) alloc(512 * 512 * 4);                // 1 MB
    float*  sc0   = (float*) alloc(512 * 4);
    float*  sh0   = (float*) alloc(512 * 4);
    float*  sc1   = (float*) alloc(256 * 4);
    float*  sh1   = (float*) alloc(256 * 4);
    (void)ws_size; (void)in_sizes; (void)n_in; (void)out_size;

    // ---- K0: zero cnt + psum1s + psq1s (contiguous) ----
    hipMemsetAsync(cnt, 0, (size_t)98304 * 4, stream);

    // ---- K1: mega prep: weights + up-invert + hist + bn0 partials + XBF ----
    mega_prep_kernel<<<3840, 256, 0, stream>>>(W_res, Ui0_W, Uj0_W, Ui1_W, Uj1_W,
                                               Ui1_b, b_res,
                                               up_row, up_col, up_val,
                                               e_dst, x,
                                               WresT, W0t, W1cat, biasUi,
                                               colof, valof, cnt, psum0, psq0, XBF);

    // ---- K2: block scan ----
    scan_block_kernel<<<256, 256, 0, stream>>>(cnt, offs, bsum);

    // ---- K3: offset add + bn0 finish ----
    add_offs_bnfin_kernel<<<384, 256, 0, stream>>>(offs, bsum, cursor,
                                                   psum0, psq0, bn0_g, bn0_b, sc0, sh0);

    // ---- K4: edge fill (packed int4) + GEMM0 (bf16 A) fused ----
    fill_gemm0_kernel<<<2816, 256, 0, stream>>>(e_src, e_dst, adjv, colof, valof,
                                                cursor, E,
                                                XBF, WresT, W0t, sc0, sh0,
                                                XW, XNJ, XNI);

    // ---- K5: ECC layer 0 aggregation + sumA + bn1 stats (persistent) ----
    gather0_kernel<<<2048, 256, 0, stream>>>(offs, cnt, E, colof, valof,
                                             XNJ, XNI, Ui0_b, Uj0_b,
                                             X1, sumA, psum1s, psq1s);

    // ---- K6: bn1 finish ----
    bn_finish_kernel<<<64, 256, 0, stream>>>(psum1s, psq1s, 64, 256, 1.0f / V_NEXT,
                                             bn1_g, bn1_b, sc1, sh1);

    // ---- K7: ECC layer 1 aggregation (commuted) ----
    gather1G_kernel<<<V_NEXT / 4, 256, 0, stream>>>(offs, cnt, E, X1, sc1, sh1, G);

    // ---- K8: final GEMM: out = [H1|G] @ W1cat + biases + residual ----
    gemm_final_kernel<<<256, 512, 0, stream>>>(X1, G, W1cat, sc1, sh1,
                                               biasUi, Uj1_b, sumA,
                                               colof, valof, XW, out);
}

// Round 17
// 238.998 us; speedup vs baseline: 1.0061x; 1.0031x over previous
//
#include <hip/hip_runtime.h>

// ---------------------------------------------------------------------------
// Problem constants
// ---------------------------------------------------------------------------
#define V_PREV 16384
#define V_NEXT 65536
#define F_IN   512
#define F_OUT  256
#define NNZ_UP 65536
#define N_EDGE 524288

using f32x4 = __attribute__((ext_vector_type(4))) float;
using bfrag = __attribute__((ext_vector_type(8))) short;   // 8 x bf16

#define LSTR 36   // LDS row stride in shorts: bank base 18*row mod 32 -> <=2-way

__device__ __forceinline__ ushort f2bf(float f) {
    union { float f; unsigned u; } v; v.f = f;
    unsigned r = (v.u + 0x7FFFu + ((v.u >> 16) & 1u)) >> 16;
    return (ushort)r;
}
__device__ __forceinline__ float bf2f(ushort h) {
    union { unsigned u; float f; } v; v.u = ((unsigned)h) << 16; return v.f;
}

// ---------------------------------------------------------------------------
// Mega K1: weight prep (0..1023) + invert_up (1024..1279)
//        + hist cnt (1280..3327) + bn0_part + XBF=bf16(x) (3328..3839)
// (cnt/psum1s/psq1s zeroed by memsetAsync BEFORE this kernel)
// ---------------------------------------------------------------------------
__global__ void mega_prep_kernel(const float* __restrict__ Wres,
                                 const float* __restrict__ Ui0W, const float* __restrict__ Uj0W,
                                 const float* __restrict__ Ui1W, const float* __restrict__ Uj1W,
                                 const float* __restrict__ Ui1b, const float* __restrict__ bres,
                                 const int* __restrict__ up_row, const int* __restrict__ up_col,
                                 const float* __restrict__ up_val,
                                 const int* __restrict__ dst,
                                 const float* __restrict__ x,
                                 ushort* __restrict__ WresT, ushort* __restrict__ W0t,
                                 ushort* __restrict__ W1cat, float* __restrict__ biasUi,
                                 int* __restrict__ colof, float* __restrict__ valof,
                                 int* __restrict__ cnt,
                                 float* __restrict__ psum0, float* __restrict__ psq0,
                                 ushort* __restrict__ XBF)
{
    int b = blockIdx.x, t = threadIdx.x;
    if (b < 1024) {
        int i = b * 256 + t;                      // 0 .. 262143
        if (i < 256 * 512) {
            int n = i / 512, k = i % 512;
            WresT[i] = f2bf(Wres[k * 256 + n]);
            W1cat[i] = f2bf(k < 256 ? Ui1W[k * 256 + n] : Uj1W[(k - 256) * 256 + n]);
        }
        {
            int n = i / 512, k = i % 512;
            W0t[i] = f2bf(n < 256 ? Uj0W[k * 256 + n] : Ui0W[k * 256 + (n - 256)]);
        }
        if (i < 256) biasUi[i] = Ui1b[i] + bres[i];
    } else if (b < 1280) {
        int k = (b - 1024) * 256 + t;             // 0 .. 65535
        int r = up_row[k];
        colof[r] = up_col[k];
        valof[r] = up_val[k];
    } else if (b < 3328) {
        int e = (b - 1280) * 256 + t;             // 0 .. 524287
        atomicAdd(&cnt[dst[e]], 1);
    } else {
        int blk = b - 3328;                        // 0..511, 32 rows each
        float s0 = 0, s1 = 0, q0 = 0, q1 = 0;
        for (int r = 0; r < 32; r++) {
            size_t base = ((size_t)blk * 32 + r) * 512;
            float a = x[base + t], bb = x[base + t + 256];
            s0 += a; q0 += a * a; s1 += bb; q1 += bb * bb;
            XBF[base + t]       = f2bf(a);
            XBF[base + t + 256] = f2bf(bb);
        }
        psum0[blk * 512 + t] = s0; psum0[blk * 512 + t + 256] = s1;
        psq0 [blk * 512 + t] = q0; psq0 [blk * 512 + t + 256] = q1;
    }
}

// ---------------------------------------------------------------------------
// CSR scan
// ---------------------------------------------------------------------------
__global__ void scan_block_kernel(const int* __restrict__ cnt, int* __restrict__ offs,
                                  int* __restrict__ bsum)
{
    __shared__ int buf[2][256];
    int t = threadIdx.x;
    int i = blockIdx.x * 256 + t;
    int v = cnt[i];
    int p = 0;
    buf[0][t] = v;
    __syncthreads();
    for (int d = 1; d < 256; d <<= 1) {
        int nv = buf[p][t] + ((t >= d) ? buf[p][t - d] : 0);
        buf[p ^ 1][t] = nv;
        p ^= 1;
        __syncthreads();
    }
    int incl = buf[p][t];
    offs[i] = incl - v;
    if (t == 255) bsum[blockIdx.x] = incl;
}

// Fat: add_offs2 (0..255) + bn0 finish (256..383, nblocks=512)
__global__ void add_offs_bnfin_kernel(int* __restrict__ offs, const int* __restrict__ bsum,
                                      int* __restrict__ cursor,
                                      const float* __restrict__ psum0, const float* __restrict__ psq0,
                                      const float* __restrict__ g0, const float* __restrict__ b0,
                                      float* __restrict__ sc0, float* __restrict__ sh0)
{
    int b = blockIdx.x, t = threadIdx.x;
    if (b < 256) {
        __shared__ int buf[2][256];
        int v = bsum[t];
        int p = 0;
        buf[0][t] = v;
        __syncthreads();
        for (int d = 1; d < 256; d <<= 1) {
            int nv = buf[p][t] + ((t >= d) ? buf[p][t - d] : 0);
            buf[p ^ 1][t] = nv;
            p ^= 1;
            __syncthreads();
        }
        int excl = buf[p][b] - bsum[b];
        int i = b * 256 + t;
        int o = offs[i] + excl;
        offs[i] = o;
        cursor[i] = o;
    } else {
        int vb = b - 256;                          // 0..127
        int gw = (vb * 256 + t) >> 6;              // channel 0..511
        int lane = t & 63;
        float s = 0, q = 0;
        for (int i = lane; i < 512; i += 64) {
            s += psum0[(size_t)i * 512 + gw];
            q += psq0 [(size_t)i * 512 + gw];
        }
#pragma unroll
        for (int d = 32; d > 0; d >>= 1) {
            s += __shfl_xor(s, d);
            q += __shfl_xor(q, d);
        }
        if (lane == 0) {
            float m = s * (1.0f / V_PREV);
            float v = q * (1.0f / V_PREV) - m * m;
            float r = rsqrtf(v + 1e-5f);
            float scale = r * g0[gw];
            sc0[gw] = scale;
            sh0[gw] = b0[gw] - m * scale;
        }
    }
}

// bn1 finish (standalone)
__global__ void bn_finish_kernel(const float* __restrict__ psum, const float* __restrict__ psq,
                                 int nblocks, int C, float invN,
                                 const float* __restrict__ g, const float* __restrict__ b,
                                 float* __restrict__ sc, float* __restrict__ sh)
{
    int gw = (blockIdx.x * blockDim.x + threadIdx.x) >> 6;
    int lane = threadIdx.x & 63;
    if (gw >= C) return;
    float s = 0, q = 0;
    for (int i = lane; i < nblocks; i += 64) {
        s += psum[(size_t)i * C + gw];
        q += psq [(size_t)i * C + gw];
    }
#pragma unroll
    for (int d = 32; d > 0; d >>= 1) {
        s += __shfl_xor(s, d);
        q += __shfl_xor(q, d);
    }
    if (lane == 0) {
        float m = s * invN;
        float v = q * invN - m * m;
        float r = rsqrtf(v + 1e-5f);
        float scale = r * g[gw];
        sc[gw] = scale;
        sh[gw] = b[gw] - m * scale;
    }
}

// ---------------------------------------------------------------------------
// Fat: gemm0 FIRST (0..767, XCD-grouped) + fill (768..2815)
// gemm0: A = XBF (bf16 copy of x); bx 0,1: XW = XBF@WresT;
//        2,3: XNJ = bn-relu(XBF)@Uj0; 4,5: XNI @Ui0
// fill: E[p] = {srcA, valA, src0=colof[s], val0=a*valof[s]}  (one 16B store)
// gemm dispatched first so MFMA work starts immediately; fill slots in after.
// ---------------------------------------------------------------------------
__global__ __launch_bounds__(256)
void fill_gemm0_kernel(const int* __restrict__ src, const int* __restrict__ dst,
                       const float* __restrict__ adjv,
                       const int* __restrict__ colof, const float* __restrict__ valof,
                       int* __restrict__ cursor, int4* __restrict__ E,
                       const ushort* __restrict__ XBF,
                       const ushort* __restrict__ WresT, const ushort* __restrict__ W0t,
                       const float* __restrict__ sc0, const float* __restrict__ sh0,
                       ushort* __restrict__ XW, ushort* __restrict__ XNJ,
                       ushort* __restrict__ XNI)
{
    __shared__ ushort As[128 * LSTR];
    __shared__ ushort Bs[128 * LSTR];
    __shared__ float s_sc[512], s_sh[512];

    const int tid = threadIdx.x;
    if (blockIdx.x >= 768) {
        int e = (blockIdx.x - 768) * 256 + tid;
        int d = dst[e];
        int s = src[e];
        float a = adjv[e];
        int p = atomicAdd(&cursor[d], 1);
        int4 v;
        v.x = s;
        v.y = __float_as_int(a);
        v.z = colof[s];
        v.w = __float_as_int(a * valof[s]);
        E[p] = v;
        return;
    }

    const int id   = blockIdx.x;               // 0..767
    const int xcd  = id & 7;
    const int rest = id >> 3;
    const int slot = rest / 6;
    const int bx   = rest - slot * 6;
    const int by   = slot * 8 + xcd;

    const bool bnmode = bx >= 2;
    const ushort* Bt = bnmode ? W0t : WresT;
    const int btrow = bnmode ? (bx - 2) * 128 : bx * 128;
    ushort* Cout = (bx < 2) ? XW : (bx < 4 ? XNJ : XNI);
    const int colbase = (bx & 1) * 128;
    const int tM = by * 128;

    for (int i = tid; i < 512; i += 256) { s_sc[i] = sc0[i]; s_sh[i] = sh0[i]; }
    __syncthreads();

    const int lane = tid & 63;
    const int wave = tid >> 6;
    const int wm = wave >> 1, wn = wave & 1;
    const int lr = lane & 15, lg = lane >> 4;

    const int ra = tid >> 1;
    const int ua = (tid & 1) * 2;
    const int rb = tid >> 2;
    const int ub = tid & 3;

    f32x4 acc[4][4] = {};

    for (int k0 = 0; k0 < 512; k0 += 32) {
        // --- A stage: 2x 8 bf16 units, optional bn+relu ---
        ushort h0[8], h1[8];
        *(uint4*)h0 = *(const uint4*)&XBF[(size_t)(tM + ra) * 512 + k0 + ua * 8];
        *(uint4*)h1 = *(const uint4*)&XBF[(size_t)(tM + ra) * 512 + k0 + (ua + 1) * 8];
        if (bnmode) {
#pragma unroll
            for (int j = 0; j < 8; j++) {
                int c0 = k0 + ua * 8 + j;
                int c1 = c0 + 8;
                h0[j] = f2bf(fmaxf(bf2f(h0[j]) * s_sc[c0] + s_sh[c0], 0.0f));
                h1[j] = f2bf(fmaxf(bf2f(h1[j]) * s_sc[c1] + s_sh[c1], 0.0f));
            }
        }
        *(uint4*)&As[ra * LSTR + ua * 8]       = *(uint4*)h0;
        *(uint4*)&As[ra * LSTR + (ua + 1) * 8] = *(uint4*)h1;

#pragma unroll
        for (int i = 0; i < 2; i++) {
            int row = rb + i * 64;
            *(uint4*)&Bs[row * LSTR + ub * 8] =
                *(const uint4*)&Bt[(size_t)(btrow + row) * 512 + k0 + ub * 8];
        }
        __syncthreads();

        bfrag af[4], bfv[4];
#pragma unroll
        for (int mm = 0; mm < 4; mm++) {
            int row = wm * 64 + mm * 16 + lr;
            af[mm] = *(const bfrag*)&As[row * LSTR + lg * 8];
        }
#pragma unroll
        for (int nn = 0; nn < 4; nn++) {
            int row = wn * 64 + nn * 16 + lr;
            bfv[nn] = *(const bfrag*)&Bs[row * LSTR + lg * 8];
        }
#pragma unroll
        for (int mm = 0; mm < 4; mm++)
#pragma unroll
            for (int nn = 0; nn < 4; nn++)
                acc[mm][nn] = __builtin_amdgcn_mfma_f32_16x16x32_bf16(af[mm], bfv[nn], acc[mm][nn], 0, 0, 0);
        __syncthreads();
    }

#pragma unroll
    for (int mm = 0; mm < 4; mm++)
#pragma unroll
        for (int nn = 0; nn < 4; nn++)
#pragma unroll
            for (int r = 0; r < 4; r++) {
                int row = tM + wm * 64 + mm * 16 + lg * 4 + r;
                int col = colbase + wn * 64 + nn * 16 + lr;
                Cout[(size_t)row * 256 + col] = f2bf(acc[mm][nn][r]);
            }
}

// ---------------------------------------------------------------------------
// Gather layer 0, persistent (2048 blocks x 8 iters), 4-wide batched loads.
// sumA computed on the fly; bn1 stats in registers.
// ---------------------------------------------------------------------------
__global__ __launch_bounds__(256)
void gather0_kernel(const int* __restrict__ offs, const int* __restrict__ cnt,
                    const int4* __restrict__ E,
                    const int* __restrict__ colof, const float* __restrict__ valof,
                    const ushort* __restrict__ XNJ, const ushort* __restrict__ XNI,
                    const float* __restrict__ ui_b, const float* __restrict__ uj_b,
                    ushort* __restrict__ X1, float* __restrict__ sumA,
                    float* __restrict__ psum1s, float* __restrict__ psq1s)
{
    __shared__ float redS[4][256];
    __shared__ float redQ[4][256];

    int wave = threadIdx.x >> 6;
    int lane = threadIdx.x & 63;
    int f = lane * 4;
    float ub0 = ui_b[f + 0], ub1 = ui_b[f + 1], ub2 = ui_b[f + 2], ub3 = ui_b[f + 3];
    float jb0 = uj_b[f + 0], jb1 = uj_b[f + 1], jb2 = uj_b[f + 2], jb3 = uj_b[f + 3];
    float ss0 = 0, ss1 = 0, ss2 = 0, ss3 = 0;
    float qq0 = 0, qq1 = 0, qq2 = 0, qq3 = 0;

    for (int it = 0; it < 8; it++) {
        int d = (blockIdx.x * 8 + it) * 4 + wave;
        int c = colof[d];
        float s = valof[d];
        ushort4 u = *(const ushort4*)&XNI[(size_t)c * 256 + f];
        const ushort* up = (const ushort*)&u;
        float a0 = ub0 + s * bf2f(up[0]);
        float a1 = ub1 + s * bf2f(up[1]);
        float a2 = ub2 + s * bf2f(up[2]);
        float a3 = ub3 + s * bf2f(up[3]);
        float sA = 0;

        int st = offs[d], n = cnt[d];
        for (int e0 = 0; e0 < n; e0 += 4) {
            int4 ev0 = E[st + e0];
            int4 ev1 = (e0 + 1 < n) ? E[st + e0 + 1] : make_int4(0, 0, 0, 0);
            int4 ev2 = (e0 + 2 < n) ? E[st + e0 + 2] : make_int4(0, 0, 0, 0);
            int4 ev3 = (e0 + 3 < n) ? E[st + e0 + 3] : make_int4(0, 0, 0, 0);
            float w0 = __int_as_float(ev0.w), w1 = __int_as_float(ev1.w);
            float w2 = __int_as_float(ev2.w), w3 = __int_as_float(ev3.w);
            sA += __int_as_float(ev0.y) + __int_as_float(ev1.y)
                + __int_as_float(ev2.y) + __int_as_float(ev3.y);
            ushort4 v0 = *(const ushort4*)&XNJ[(size_t)ev0.z * 256 + f];
            ushort4 v1 = *(const ushort4*)&XNJ[(size_t)ev1.z * 256 + f];
            ushort4 v2 = *(const ushort4*)&XNJ[(size_t)ev2.z * 256 + f];
            ushort4 v3 = *(const ushort4*)&XNJ[(size_t)ev3.z * 256 + f];
            const ushort* p0 = (const ushort*)&v0;
            const ushort* p1 = (const ushort*)&v1;
            const ushort* p2 = (const ushort*)&v2;
            const ushort* p3 = (const ushort*)&v3;
            a0 += w0 * bf2f(p0[0]) + w1 * bf2f(p1[0]) + w2 * bf2f(p2[0]) + w3 * bf2f(p3[0]);
            a1 += w0 * bf2f(p0[1]) + w1 * bf2f(p1[1]) + w2 * bf2f(p2[1]) + w3 * bf2f(p3[1]);
            a2 += w0 * bf2f(p0[2]) + w1 * bf2f(p1[2]) + w2 * bf2f(p2[2]) + w3 * bf2f(p3[2]);
            a3 += w0 * bf2f(p0[3]) + w1 * bf2f(p1[3]) + w2 * bf2f(p2[3]) + w3 * bf2f(p3[3]);
        }
        a0 += sA * jb0; a1 += sA * jb1; a2 += sA * jb2; a3 += sA * jb3;
        *(ushort4*)&X1[(size_t)d * 256 + f] =
            make_ushort4(f2bf(a0), f2bf(a1), f2bf(a2), f2bf(a3));
        if (lane == 0) sumA[d] = sA;
        ss0 += a0; ss1 += a1; ss2 += a2; ss3 += a3;
        qq0 += a0 * a0; qq1 += a1 * a1; qq2 += a2 * a2; qq3 += a3 * a3;
    }

    redS[wave][f + 0] = ss0; redS[wave][f + 1] = ss1;
    redS[wave][f + 2] = ss2; redS[wave][f + 3] = ss3;
    redQ[wave][f + 0] = qq0; redQ[wave][f + 1] = qq1;
    redQ[wave][f + 2] = qq2; redQ[wave][f + 3] = qq3;
    __syncthreads();
    int t = threadIdx.x;   // channel
    float ssum = redS[0][t] + redS[1][t] + redS[2][t] + redS[3][t];
    float sq   = redQ[0][t] + redQ[1][t] + redQ[2][t] + redQ[3][t];
    int slab = (blockIdx.x & 63) * 256 + t;
    atomicAdd(&psum1s[slab], ssum);
    atomicAdd(&psq1s[slab], sq);
}

// ---------------------------------------------------------------------------
// Gather layer 1 (pre-GEMM, bn1+relu folded), TWO independent dst chains per
// wave (d and d+4): doubles outstanding row loads without lengthening chains.
//   G[d] = sum_e valA * relu(sc1*X1[srcA] + sh1)     (bf16 out)
// ---------------------------------------------------------------------------
__global__ __launch_bounds__(256)
void gather1G_kernel(const int* __restrict__ offs, const int* __restrict__ cnt,
                     const int4* __restrict__ E,
                     const ushort* __restrict__ X1,
                     const float* __restrict__ sc1, const float* __restrict__ sh1,
                     ushort* __restrict__ G)
{
    int base = blockIdx.x * 8 + (threadIdx.x >> 6);
    int d0 = base, d1 = base + 4;
    int f = (threadIdx.x & 63) * 4;
    float4 sc = *(const float4*)&sc1[f];
    float4 sh = *(const float4*)&sh1[f];
    float a00 = 0, a01 = 0, a02 = 0, a03 = 0;
    float a10 = 0, a11 = 0, a12 = 0, a13 = 0;

    int st0 = offs[d0], n0 = cnt[d0];
    int st1 = offs[d1], n1 = cnt[d1];
    int nmax = max(n0, n1);

    for (int e0 = 0; e0 < nmax; e0 += 2) {
        // chain 0: 2 edges
        int4 ea0 = (e0     < n0) ? E[st0 + e0]     : make_int4(0, 0, 0, 0);
        int4 ea1 = (e0 + 1 < n0) ? E[st0 + e0 + 1] : make_int4(0, 0, 0, 0);
        // chain 1: 2 edges
        int4 eb0 = (e0     < n1) ? E[st1 + e0]     : make_int4(0, 0, 0, 0);
        int4 eb1 = (e0 + 1 < n1) ? E[st1 + e0 + 1] : make_int4(0, 0, 0, 0);
        // 4 independent row loads
        ushort4 va0 = *(const ushort4*)&X1[(size_t)ea0.x * 256 + f];
        ushort4 va1 = *(const ushort4*)&X1[(size_t)ea1.x * 256 + f];
        ushort4 vb0 = *(const ushort4*)&X1[(size_t)eb0.x * 256 + f];
        ushort4 vb1 = *(const ushort4*)&X1[(size_t)eb1.x * 256 + f];
        float wa0 = __int_as_float(ea0.y), wa1 = __int_as_float(ea1.y);
        float wb0 = __int_as_float(eb0.y), wb1 = __int_as_float(eb1.y);
        const ushort* pa0 = (const ushort*)&va0;
        const ushort* pa1 = (const ushort*)&va1;
        const ushort* pb0 = (const ushort*)&vb0;
        const ushort* pb1 = (const ushort*)&vb1;
        a00 += wa0 * fmaxf(bf2f(pa0[0]) * sc.x + sh.x, 0.0f)
             + wa1 * fmaxf(bf2f(pa1[0]) * sc.x + sh.x, 0.0f);
        a01 += wa0 * fmaxf(bf2f(pa0[1]) * sc.y + sh.y, 0.0f)
             + wa1 * fmaxf(bf2f(pa1[1]) * sc.y + sh.y, 0.0f);
        a02 += wa0 * fmaxf(bf2f(pa0[2]) * sc.z + sh.z, 0.0f)
             + wa1 * fmaxf(bf2f(pa1[2]) * sc.z + sh.z, 0.0f);
        a03 += wa0 * fmaxf(bf2f(pa0[3]) * sc.w + sh.w, 0.0f)
             + wa1 * fmaxf(bf2f(pa1[3]) * sc.w + sh.w, 0.0f);
        a10 += wb0 * fmaxf(bf2f(pb0[0]) * sc.x + sh.x, 0.0f)
             + wb1 * fmaxf(bf2f(pb1[0]) * sc.x + sh.x, 0.0f);
        a11 += wb0 * fmaxf(bf2f(pb0[1]) * sc.y + sh.y, 0.0f)
             + wb1 * fmaxf(bf2f(pb1[1]) * sc.y + sh.y, 0.0f);
        a12 += wb0 * fmaxf(bf2f(pb0[2]) * sc.z + sh.z, 0.0f)
             + wb1 * fmaxf(bf2f(pb1[2]) * sc.z + sh.z, 0.0f);
        a13 += wb0 * fmaxf(bf2f(pb0[3]) * sc.w + sh.w, 0.0f)
             + wb1 * fmaxf(bf2f(pb1[3]) * sc.w + sh.w, 0.0f);
    }
    *(ushort4*)&G[(size_t)d0 * 256 + f] =
        make_ushort4(f2bf(a00), f2bf(a01), f2bf(a02), f2bf(a03));
    *(ushort4*)&G[(size_t)d1 * 256 + f] =
        make_ushort4(f2bf(a10), f2bf(a11), f2bf(a12), f2bf(a13));
}

// ---------------------------------------------------------------------------
// GEMM final: out[65536,256] f32 = [relu(bn1(X1)) | G] @ W1cat^T + biases + res
// 256x256 tile, 512 thr, grid 256. LDS stride 36.
// ---------------------------------------------------------------------------
__global__ __launch_bounds__(512, 1)
void gemm_final_kernel(const ushort* __restrict__ X1, const ushort* __restrict__ G,
                       const ushort* __restrict__ W1cat,
                       const float* __restrict__ sc1, const float* __restrict__ sh1,
                       const float* __restrict__ biasUi, const float* __restrict__ uj1_b,
                       const float* __restrict__ sumA,
                       const int* __restrict__ colof, const float* __restrict__ valof,
                       const ushort* __restrict__ XW,
                       float* __restrict__ out)
{
    __shared__ ushort As[256 * LSTR];
    __shared__ ushort Bs[256 * LSTR];
    __shared__ float s_sc[256], s_sh[256];

    const int tid = threadIdx.x;
    const int tM = blockIdx.x * 256;

    if (tid < 256) { s_sc[tid] = sc1[tid]; s_sh[tid] = sh1[tid]; }
    __syncthreads();

    const int lane = tid & 63;
    const int wave = tid >> 6;
    const int wm = wave >> 1, wn = wave & 1;    // wave tile 64 rows x 128 cols
    const int lr = lane & 15, lg = lane >> 4;

    f32x4 acc[4][8] = {};

    for (int k0 = 0; k0 < 512; k0 += 32) {
#pragma unroll
        for (int i = 0; i < 2; i++) {
            int idx = tid + i * 512;
            int row = idx >> 2, u = idx & 3;
            ushort h[8];
            if (k0 < 256) {
                *(uint4*)h = *(const uint4*)&X1[(size_t)(tM + row) * 256 + k0 + u * 8];
#pragma unroll
                for (int j = 0; j < 8; j++) {
                    int c = k0 + u * 8 + j;
                    h[j] = f2bf(fmaxf(bf2f(h[j]) * s_sc[c] + s_sh[c], 0.0f));
                }
            } else {
                *(uint4*)h = *(const uint4*)&G[(size_t)(tM + row) * 256 + (k0 - 256) + u * 8];
            }
            *(uint4*)&As[row * LSTR + u * 8] = *(uint4*)h;
        }
#pragma unroll
        for (int i = 0; i < 2; i++) {
            int idx = tid + i * 512;
            int row = idx >> 2, u = idx & 3;
            *(uint4*)&Bs[row * LSTR + u * 8] =
                *(const uint4*)&W1cat[(size_t)row * 512 + k0 + u * 8];
        }
        __syncthreads();

        bfrag af[4], bfv[8];
#pragma unroll
        for (int mm = 0; mm < 4; mm++) {
            int row = wm * 64 + mm * 16 + lr;
            af[mm] = *(const bfrag*)&As[row * LSTR + lg * 8];
        }
#pragma unroll
        for (int nn = 0; nn < 8; nn++) {
            int row = wn * 128 + nn * 16 + lr;
            bfv[nn] = *(const bfrag*)&Bs[row * LSTR + lg * 8];
        }
#pragma unroll
        for (int mm = 0; mm < 4; mm++)
#pragma unroll
            for (int nn = 0; nn < 8; nn++)
                acc[mm][nn] = __builtin_amdgcn_mfma_f32_16x16x32_bf16(af[mm], bfv[nn], acc[mm][nn], 0, 0, 0);
        __syncthreads();
    }

    float bUi[8], bUj[8];
#pragma unroll
    for (int nn = 0; nn < 8; nn++) {
        int col = wn * 128 + nn * 16 + lr;
        bUi[nn] = biasUi[col];
        bUj[nn] = uj1_b[col];
    }
#pragma unroll
    for (int mm = 0; mm < 4; mm++) {
#pragma unroll
        for (int r = 0; r < 4; r++) {
            int row = tM + wm * 64 + mm * 16 + lg * 4 + r;
            int c = colof[row];
            float s = valof[row];
            float sA = sumA[row];
#pragma unroll
            for (int nn = 0; nn < 8; nn++) {
                int col = wn * 128 + nn * 16 + lr;
                float v = acc[mm][nn][r] + bUi[nn] + sA * bUj[nn]
                        + s * bf2f(XW[(size_t)c * 256 + col]);
                out[(size_t)row * 256 + col] = v;
            }
        }
    }
}

// ---------------------------------------------------------------------------
// Host launcher
// ---------------------------------------------------------------------------
extern "C" void kernel_launch(void* const* d_in, const int* in_sizes, int n_in,
                              void* d_out, int out_size, void* d_ws, size_t ws_size,
                              hipStream_t stream)
{
    const float* x      = (const float*)d_in[0];
    const int*   up_row = (const int*)  d_in[1];
    const int*   up_col = (const int*)  d_in[2];
    const float* up_val = (const float*)d_in[3];
    const int*   e_src  = (const int*)  d_in[4];
    const int*   e_dst  = (const int*)  d_in[5];
    const float* adjv   = (const float*)d_in[6];
    const float* W_res  = (const float*)d_in[7];
    const float* b_res  = (const float*)d_in[8];
    const float* bn0_g  = (const float*)d_in[9];
    const float* bn0_b  = (const float*)d_in[10];
    const float* bn1_g  = (const float*)d_in[11];
    const float* bn1_b  = (const float*)d_in[12];
    const float* Ui0_W  = (const float*)d_in[13];
    const float* Ui0_b  = (const float*)d_in[14];
    const float* Uj0_W  = (const float*)d_in[15];
    const float* Uj0_b  = (const float*)d_in[16];
    const float* Ui1_W  = (const float*)d_in[17];
    const float* Ui1_b  = (const float*)d_in[18];
    const float* Uj1_W  = (const float*)d_in[19];
    const float* Uj1_b  = (const float*)d_in[20];

    float* out = (float*)d_out;

    // ---- workspace layout ----
    char* ws = (char*)d_ws;
    size_t off = 0;
    auto alloc = [&](size_t bytes) -> char* {
        char* p = ws + off;
        off = (off + bytes + 255) & ~(size_t)255;
        return p;
    };
    ushort* XW    = (ushort*)alloc((size_t)V_PREV * F_OUT * 2);   // 8.4 MB
    ushort* XNJ   = (ushort*)alloc((size_t)V_PREV * F_OUT * 2);   // 8.4 MB
    ushort* XNI   = (ushort*)alloc((size_t)V_PREV * F_OUT * 2);   // 8.4 MB
    ushort* XBF   = (ushort*)alloc((size_t)V_PREV * F_IN * 2);    // 16.8 MB
    ushort* X1    = (ushort*)alloc((size_t)V_NEXT * F_OUT * 2);   // 33.6 MB
    ushort* G     = (ushort*)alloc((size_t)V_NEXT * F_OUT * 2);   // 33.6 MB
    // --- zeroed region (memsetAsync): cnt, psum1s, psq1s = 98304 ints ---
    int*    cnt   = (int*)   alloc(V_NEXT * 4);                   // 256 KB
    float*  psum1s= (float*) alloc(64 * 256 * 4);                 // 64 KB
    float*  psq1s = (float*) alloc(64 * 256 * 4);                 // 64 KB
    float*  sumA  = (float*) alloc(V_NEXT * 4);
    int*    offs  = (int*)   alloc(V_NEXT * 4);
    int*    cursor= (int*)   alloc(V_NEXT * 4);
    int*    bsum  = (int*)   alloc(256 * 4);
    int4*   E     = (int4*)  alloc((size_t)N_EDGE * 16);          // 8.4 MB
    int*    colof = (int*)   alloc(V_NEXT * 4);
    float*  valof = (float*) alloc(V_NEXT * 4);
    ushort* WresT = (ushort*)alloc(256 * 512 * 2);
    ushort* W0t   = (ushort*)alloc(512 * 512 * 2);
    ushort* W1cat = (ushort*)alloc(256 * 512 * 2);
    float*  biasUi= (float*) alloc(256 * 4);
    float*  psum0 = (float*) alloc(512 * 512 * 4);                // 1 MB
    float*  psq0  = (float*) alloc(512 * 512 * 4);                // 1 MB
    float*  sc0   = (float*) alloc(512 * 4);
    float*  sh0   = (float*) alloc(512 * 4);
    float*  sc1   = (float*) alloc(256 * 4);
    float*  sh1   = (float*) alloc(256 * 4);
    (void)ws_size; (void)in_sizes; (void)n_in; (void)out_size;

    // ---- K0: zero cnt + psum1s + psq1s (contiguous) ----
    hipMemsetAsync(cnt, 0, (size_t)98304 * 4, stream);

    // ---- K1: mega prep: weights + up-invert + hist + bn0 partials + XBF ----
    mega_prep_kernel<<<3840, 256, 0, stream>>>(W_res, Ui0_W, Uj0_W, Ui1_W, Uj1_W,
                                               Ui1_b, b_res,
                                               up_row, up_col, up_val,
                                               e_dst, x,
                                               WresT, W0t, W1cat, biasUi,
                                               colof, valof, cnt, psum0, psq0, XBF);

    // ---- K2: block scan ----
    scan_block_kernel<<<256, 256, 0, stream>>>(cnt, offs, bsum);

    // ---- K3: offset add + bn0 finish ----
    add_offs_bnfin_kernel<<<384, 256, 0, stream>>>(offs, bsum, cursor,
                                                   psum0, psq0, bn0_g, bn0_b, sc0, sh0);

    // ---- K4: GEMM0 (bf16 A, blocks 0..767) + edge fill (768..2815) ----
    fill_gemm0_kernel<<<2816, 256, 0, stream>>>(e_src, e_dst, adjv, colof, valof,
                                                cursor, E,
                                                XBF, WresT, W0t, sc0, sh0,
                                                XW, XNJ, XNI);

    // ---- K5: ECC layer 0 aggregation + sumA + bn1 stats (persistent) ----
    gather0_kernel<<<2048, 256, 0, stream>>>(offs, cnt, E, colof, valof,
                                             XNJ, XNI, Ui0_b, Uj0_b,
                                             X1, sumA, psum1s, psq1s);

    // ---- K6: bn1 finish ----
    bn_finish_kernel<<<64, 256, 0, stream>>>(psum1s, psq1s, 64, 256, 1.0f / V_NEXT,
                                             bn1_g, bn1_b, sc1, sh1);

    // ---- K7: ECC layer 1 aggregation (commuted, 2 chains/wave) ----
    gather1G_kernel<<<V_NEXT / 8, 256, 0, stream>>>(offs, cnt, E, X1, sc1, sh1, G);

    // ---- K8: final GEMM: out = [H1|G] @ W1cat + biases + residual ----
    gemm_final_kernel<<<256, 512, 0, stream>>>(X1, G, W1cat, sc1, sh1,
                                               biasUi, Uj1_b, sumA,
                                               colof, valof, XW, out);
}

// Round 18
// 231.680 us; speedup vs baseline: 1.0379x; 1.0316x over previous
//
#include <hip/hip_runtime.h>

// ---------------------------------------------------------------------------
// Problem constants
// ---------------------------------------------------------------------------
#define V_PREV 16384
#define V_NEXT 65536
#define F_IN   512
#define F_OUT  256
#define NNZ_UP 65536
#define N_EDGE 524288

using f32x4 = __attribute__((ext_vector_type(4))) float;
using bfrag = __attribute__((ext_vector_type(8))) short;   // 8 x bf16

#define LSTR 36   // LDS row stride in shorts: bank base 18*row mod 32 -> <=2-way

__device__ __forceinline__ ushort f2bf(float f) {
    union { float f; unsigned u; } v; v.f = f;
    unsigned r = (v.u + 0x7FFFu + ((v.u >> 16) & 1u)) >> 16;
    return (ushort)r;
}
__device__ __forceinline__ float bf2f(ushort h) {
    union { unsigned u; float f; } v; v.u = ((unsigned)h) << 16; return v.f;
}

// ---------------------------------------------------------------------------
// Mega K1: weight prep (0..1023) + invert_up (1024..1279)
//        + hist cnt (1280..3327) + bn0_part + XBF=bf16(x) (3328..3839)
// ---------------------------------------------------------------------------
__global__ void mega_prep_kernel(const float* __restrict__ Wres,
                                 const float* __restrict__ Ui0W, const float* __restrict__ Uj0W,
                                 const float* __restrict__ Ui1W, const float* __restrict__ Uj1W,
                                 const float* __restrict__ Ui1b, const float* __restrict__ bres,
                                 const int* __restrict__ up_row, const int* __restrict__ up_col,
                                 const float* __restrict__ up_val,
                                 const int* __restrict__ dst,
                                 const float* __restrict__ x,
                                 ushort* __restrict__ WresT, ushort* __restrict__ W0t,
                                 ushort* __restrict__ W1cat, float* __restrict__ biasUi,
                                 int* __restrict__ colof, float* __restrict__ valof,
                                 int* __restrict__ cnt,
                                 float* __restrict__ psum0, float* __restrict__ psq0,
                                 ushort* __restrict__ XBF)
{
    int b = blockIdx.x, t = threadIdx.x;
    if (b < 1024) {
        int i = b * 256 + t;                      // 0 .. 262143
        if (i < 256 * 512) {
            int n = i / 512, k = i % 512;
            WresT[i] = f2bf(Wres[k * 256 + n]);
            W1cat[i] = f2bf(k < 256 ? Ui1W[k * 256 + n] : Uj1W[(k - 256) * 256 + n]);
        }
        {
            int n = i / 512, k = i % 512;
            W0t[i] = f2bf(n < 256 ? Uj0W[k * 256 + n] : Ui0W[k * 256 + (n - 256)]);
        }
        if (i < 256) biasUi[i] = Ui1b[i] + bres[i];
    } else if (b < 1280) {
        int k = (b - 1024) * 256 + t;             // 0 .. 65535
        int r = up_row[k];
        colof[r] = up_col[k];
        valof[r] = up_val[k];
    } else if (b < 3328) {
        int e = (b - 1280) * 256 + t;             // 0 .. 524287
        atomicAdd(&cnt[dst[e]], 1);
    } else {
        int blk = b - 3328;                        // 0..511, 32 rows each
        float s0 = 0, s1 = 0, q0 = 0, q1 = 0;
        for (int r = 0; r < 32; r++) {
            size_t base = ((size_t)blk * 32 + r) * 512;
            float a = x[base + t], bb = x[base + t + 256];
            s0 += a; q0 += a * a; s1 += bb; q1 += bb * bb;
            XBF[base + t]       = f2bf(a);
            XBF[base + t + 256] = f2bf(bb);
        }
        psum0[blk * 512 + t] = s0; psum0[blk * 512 + t + 256] = s1;
        psq0 [blk * 512 + t] = q0; psq0 [blk * 512 + t + 256] = q1;
    }
}

// ---------------------------------------------------------------------------
// CSR scan
// ---------------------------------------------------------------------------
__global__ void scan_block_kernel(const int* __restrict__ cnt, int* __restrict__ offs,
                                  int* __restrict__ bsum)
{
    __shared__ int buf[2][256];
    int t = threadIdx.x;
    int i = blockIdx.x * 256 + t;
    int v = cnt[i];
    int p = 0;
    buf[0][t] = v;
    __syncthreads();
    for (int d = 1; d < 256; d <<= 1) {
        int nv = buf[p][t] + ((t >= d) ? buf[p][t - d] : 0);
        buf[p ^ 1][t] = nv;
        p ^= 1;
        __syncthreads();
    }
    int incl = buf[p][t];
    offs[i] = incl - v;
    if (t == 255) bsum[blockIdx.x] = incl;
}

// Fat: add_offs2 (0..255) + bn0 finish (256..383, nblocks=512)
__global__ void add_offs_bnfin_kernel(int* __restrict__ offs, const int* __restrict__ bsum,
                                      int* __restrict__ cursor,
                                      const float* __restrict__ psum0, const float* __restrict__ psq0,
                                      const float* __restrict__ g0, const float* __restrict__ b0,
                                      float* __restrict__ sc0, float* __restrict__ sh0)
{
    int b = blockIdx.x, t = threadIdx.x;
    if (b < 256) {
        __shared__ int buf[2][256];
        int v = bsum[t];
        int p = 0;
        buf[0][t] = v;
        __syncthreads();
        for (int d = 1; d < 256; d <<= 1) {
            int nv = buf[p][t] + ((t >= d) ? buf[p][t - d] : 0);
            buf[p ^ 1][t] = nv;
            p ^= 1;
            __syncthreads();
        }
        int excl = buf[p][b] - bsum[b];
        int i = b * 256 + t;
        int o = offs[i] + excl;
        offs[i] = o;
        cursor[i] = o;
    } else {
        int vb = b - 256;                          // 0..127
        int gw = (vb * 256 + t) >> 6;              // channel 0..511
        int lane = t & 63;
        float s = 0, q = 0;
        for (int i = lane; i < 512; i += 64) {
            s += psum0[(size_t)i * 512 + gw];
            q += psq0 [(size_t)i * 512 + gw];
        }
#pragma unroll
        for (int d = 32; d > 0; d >>= 1) {
            s += __shfl_xor(s, d);
            q += __shfl_xor(q, d);
        }
        if (lane == 0) {
            float m = s * (1.0f / V_PREV);
            float v = q * (1.0f / V_PREV) - m * m;
            float r = rsqrtf(v + 1e-5f);
            float scale = r * g0[gw];
            sc0[gw] = scale;
            sh0[gw] = b0[gw] - m * scale;
        }
    }
}

// bn1 finish (standalone)
__global__ void bn_finish_kernel(const float* __restrict__ psum, const float* __restrict__ psq,
                                 int nblocks, int C, float invN,
                                 const float* __restrict__ g, const float* __restrict__ b,
                                 float* __restrict__ sc, float* __restrict__ sh)
{
    int gw = (blockIdx.x * blockDim.x + threadIdx.x) >> 6;
    int lane = threadIdx.x & 63;
    if (gw >= C) return;
    float s = 0, q = 0;
    for (int i = lane; i < nblocks; i += 64) {
        s += psum[(size_t)i * C + gw];
        q += psq [(size_t)i * C + gw];
    }
#pragma unroll
    for (int d = 32; d > 0; d >>= 1) {
        s += __shfl_xor(s, d);
        q += __shfl_xor(q, d);
    }
    if (lane == 0) {
        float m = s * invN;
        float v = q * invN - m * m;
        float r = rsqrtf(v + 1e-5f);
        float scale = r * g[gw];
        sc[gw] = scale;
        sh[gw] = b[gw] - m * scale;
    }
}

// ---------------------------------------------------------------------------
// Fat: gemm0 FIRST (0..767, XCD-grouped) + fill (768..2815)
// gemm0: A = XBF (bf16 copy of x); bx 0,1: XW = XBF@WresT;
//        2,3: XNJ = bn-relu(XBF)@Uj0; 4,5: XNI @Ui0
// fill: E[p] = {srcA, valA, src0=colof[s], val0=a*valof[s]}  (one 16B store)
// ---------------------------------------------------------------------------
__global__ __launch_bounds__(256)
void fill_gemm0_kernel(const int* __restrict__ src, const int* __restrict__ dst,
                       const float* __restrict__ adjv,
                       const int* __restrict__ colof, const float* __restrict__ valof,
                       int* __restrict__ cursor, int4* __restrict__ E,
                       const ushort* __restrict__ XBF,
                       const ushort* __restrict__ WresT, const ushort* __restrict__ W0t,
                       const float* __restrict__ sc0, const float* __restrict__ sh0,
                       ushort* __restrict__ XW, ushort* __restrict__ XNJ,
                       ushort* __restrict__ XNI)
{
    __shared__ ushort As[128 * LSTR];
    __shared__ ushort Bs[128 * LSTR];
    __shared__ float s_sc[512], s_sh[512];

    const int tid = threadIdx.x;
    if (blockIdx.x >= 768) {
        int e = (blockIdx.x - 768) * 256 + tid;
        int d = dst[e];
        int s = src[e];
        float a = adjv[e];
        int p = atomicAdd(&cursor[d], 1);
        int4 v;
        v.x = s;
        v.y = __float_as_int(a);
        v.z = colof[s];
        v.w = __float_as_int(a * valof[s]);
        E[p] = v;
        return;
    }

    const int id   = blockIdx.x;               // 0..767
    const int xcd  = id & 7;
    const int rest = id >> 3;
    const int slot = rest / 6;
    const int bx   = rest - slot * 6;
    const int by   = slot * 8 + xcd;

    const bool bnmode = bx >= 2;
    const ushort* Bt = bnmode ? W0t : WresT;
    const int btrow = bnmode ? (bx - 2) * 128 : bx * 128;
    ushort* Cout = (bx < 2) ? XW : (bx < 4 ? XNJ : XNI);
    const int colbase = (bx & 1) * 128;
    const int tM = by * 128;

    for (int i = tid; i < 512; i += 256) { s_sc[i] = sc0[i]; s_sh[i] = sh0[i]; }
    __syncthreads();

    const int lane = tid & 63;
    const int wave = tid >> 6;
    const int wm = wave >> 1, wn = wave & 1;
    const int lr = lane & 15, lg = lane >> 4;

    const int ra = tid >> 1;
    const int ua = (tid & 1) * 2;
    const int rb = tid >> 2;
    const int ub = tid & 3;

    f32x4 acc[4][4] = {};

    for (int k0 = 0; k0 < 512; k0 += 32) {
        ushort h0[8], h1[8];
        *(uint4*)h0 = *(const uint4*)&XBF[(size_t)(tM + ra) * 512 + k0 + ua * 8];
        *(uint4*)h1 = *(const uint4*)&XBF[(size_t)(tM + ra) * 512 + k0 + (ua + 1) * 8];
        if (bnmode) {
#pragma unroll
            for (int j = 0; j < 8; j++) {
                int c0 = k0 + ua * 8 + j;
                int c1 = c0 + 8;
                h0[j] = f2bf(fmaxf(bf2f(h0[j]) * s_sc[c0] + s_sh[c0], 0.0f));
                h1[j] = f2bf(fmaxf(bf2f(h1[j]) * s_sc[c1] + s_sh[c1], 0.0f));
            }
        }
        *(uint4*)&As[ra * LSTR + ua * 8]       = *(uint4*)h0;
        *(uint4*)&As[ra * LSTR + (ua + 1) * 8] = *(uint4*)h1;

#pragma unroll
        for (int i = 0; i < 2; i++) {
            int row = rb + i * 64;
            *(uint4*)&Bs[row * LSTR + ub * 8] =
                *(const uint4*)&Bt[(size_t)(btrow + row) * 512 + k0 + ub * 8];
        }
        __syncthreads();

        bfrag af[4], bfv[4];
#pragma unroll
        for (int mm = 0; mm < 4; mm++) {
            int row = wm * 64 + mm * 16 + lr;
            af[mm] = *(const bfrag*)&As[row * LSTR + lg * 8];
        }
#pragma unroll
        for (int nn = 0; nn < 4; nn++) {
            int row = wn * 64 + nn * 16 + lr;
            bfv[nn] = *(const bfrag*)&Bs[row * LSTR + lg * 8];
        }
#pragma unroll
        for (int mm = 0; mm < 4; mm++)
#pragma unroll
            for (int nn = 0; nn < 4; nn++)
                acc[mm][nn] = __builtin_amdgcn_mfma_f32_16x16x32_bf16(af[mm], bfv[nn], acc[mm][nn], 0, 0, 0);
        __syncthreads();
    }

#pragma unroll
    for (int mm = 0; mm < 4; mm++)
#pragma unroll
        for (int nn = 0; nn < 4; nn++)
#pragma unroll
            for (int r = 0; r < 4; r++) {
                int row = tM + wm * 64 + mm * 16 + lg * 4 + r;
                int col = colbase + wn * 64 + nn * 16 + lr;
                Cout[(size_t)row * 256 + col] = f2bf(acc[mm][nn][r]);
            }
}

// ---------------------------------------------------------------------------
// Gather layer 0, persistent (2048 blocks x 8 iters), 4-wide batched loads.
// sumA computed on the fly; bn1 stats in registers.
// ---------------------------------------------------------------------------
__global__ __launch_bounds__(256)
void gather0_kernel(const int* __restrict__ offs, const int* __restrict__ cnt,
                    const int4* __restrict__ E,
                    const int* __restrict__ colof, const float* __restrict__ valof,
                    const ushort* __restrict__ XNJ, const ushort* __restrict__ XNI,
                    const float* __restrict__ ui_b, const float* __restrict__ uj_b,
                    ushort* __restrict__ X1, float* __restrict__ sumA,
                    float* __restrict__ psum1s, float* __restrict__ psq1s)
{
    __shared__ float redS[4][256];
    __shared__ float redQ[4][256];

    int wave = threadIdx.x >> 6;
    int lane = threadIdx.x & 63;
    int f = lane * 4;
    float ub0 = ui_b[f + 0], ub1 = ui_b[f + 1], ub2 = ui_b[f + 2], ub3 = ui_b[f + 3];
    float jb0 = uj_b[f + 0], jb1 = uj_b[f + 1], jb2 = uj_b[f + 2], jb3 = uj_b[f + 3];
    float ss0 = 0, ss1 = 0, ss2 = 0, ss3 = 0;
    float qq0 = 0, qq1 = 0, qq2 = 0, qq3 = 0;

    for (int it = 0; it < 8; it++) {
        int d = (blockIdx.x * 8 + it) * 4 + wave;
        int c = colof[d];
        float s = valof[d];
        ushort4 u = *(const ushort4*)&XNI[(size_t)c * 256 + f];
        const ushort* up = (const ushort*)&u;
        float a0 = ub0 + s * bf2f(up[0]);
        float a1 = ub1 + s * bf2f(up[1]);
        float a2 = ub2 + s * bf2f(up[2]);
        float a3 = ub3 + s * bf2f(up[3]);
        float sA = 0;

        int st = offs[d], n = cnt[d];
        for (int e0 = 0; e0 < n; e0 += 4) {
            int4 ev0 = E[st + e0];
            int4 ev1 = (e0 + 1 < n) ? E[st + e0 + 1] : make_int4(0, 0, 0, 0);
            int4 ev2 = (e0 + 2 < n) ? E[st + e0 + 2] : make_int4(0, 0, 0, 0);
            int4 ev3 = (e0 + 3 < n) ? E[st + e0 + 3] : make_int4(0, 0, 0, 0);
            float w0 = __int_as_float(ev0.w), w1 = __int_as_float(ev1.w);
            float w2 = __int_as_float(ev2.w), w3 = __int_as_float(ev3.w);
            sA += __int_as_float(ev0.y) + __int_as_float(ev1.y)
                + __int_as_float(ev2.y) + __int_as_float(ev3.y);
            ushort4 v0 = *(const ushort4*)&XNJ[(size_t)ev0.z * 256 + f];
            ushort4 v1 = *(const ushort4*)&XNJ[(size_t)ev1.z * 256 + f];
            ushort4 v2 = *(const ushort4*)&XNJ[(size_t)ev2.z * 256 + f];
            ushort4 v3 = *(const ushort4*)&XNJ[(size_t)ev3.z * 256 + f];
            const ushort* p0 = (const ushort*)&v0;
            const ushort* p1 = (const ushort*)&v1;
            const ushort* p2 = (const ushort*)&v2;
            const ushort* p3 = (const ushort*)&v3;
            a0 += w0 * bf2f(p0[0]) + w1 * bf2f(p1[0]) + w2 * bf2f(p2[0]) + w3 * bf2f(p3[0]);
            a1 += w0 * bf2f(p0[1]) + w1 * bf2f(p1[1]) + w2 * bf2f(p2[1]) + w3 * bf2f(p3[1]);
            a2 += w0 * bf2f(p0[2]) + w1 * bf2f(p1[2]) + w2 * bf2f(p2[2]) + w3 * bf2f(p3[2]);
            a3 += w0 * bf2f(p0[3]) + w1 * bf2f(p1[3]) + w2 * bf2f(p2[3]) + w3 * bf2f(p3[3]);
        }
        a0 += sA * jb0; a1 += sA * jb1; a2 += sA * jb2; a3 += sA * jb3;
        *(ushort4*)&X1[(size_t)d * 256 + f] =
            make_ushort4(f2bf(a0), f2bf(a1), f2bf(a2), f2bf(a3));
        if (lane == 0) sumA[d] = sA;
        ss0 += a0; ss1 += a1; ss2 += a2; ss3 += a3;
        qq0 += a0 * a0; qq1 += a1 * a1; qq2 += a2 * a2; qq3 += a3 * a3;
    }

    redS[wave][f + 0] = ss0; redS[wave][f + 1] = ss1;
    redS[wave][f + 2] = ss2; redS[wave][f + 3] = ss3;
    redQ[wave][f + 0] = qq0; redQ[wave][f + 1] = qq1;
    redQ[wave][f + 2] = qq2; redQ[wave][f + 3] = qq3;
    __syncthreads();
    int t = threadIdx.x;   // channel
    float ssum = redS[0][t] + redS[1][t] + redS[2][t] + redS[3][t];
    float sq   = redQ[0][t] + redQ[1][t] + redQ[2][t] + redQ[3][t];
    int slab = (blockIdx.x & 63) * 256 + t;
    atomicAdd(&psum1s[slab], ssum);
    atomicAdd(&psq1s[slab], sq);
}

// ---------------------------------------------------------------------------
// Gather layer 1 (pre-GEMM, bn1+relu folded), persistent (2048 blocks x 8),
// 4-wide single chain (proven R16 inner loop):
//   G[d] = sum_e valA * relu(sc1*X1[srcA] + sh1)     (bf16 out)
// ---------------------------------------------------------------------------
__global__ __launch_bounds__(256)
void gather1G_kernel(const int* __restrict__ offs, const int* __restrict__ cnt,
                     const int4* __restrict__ E,
                     const ushort* __restrict__ X1,
                     const float* __restrict__ sc1, const float* __restrict__ sh1,
                     ushort* __restrict__ G)
{
    int wave = threadIdx.x >> 6;
    int f = (threadIdx.x & 63) * 4;
    float4 sc = *(const float4*)&sc1[f];
    float4 sh = *(const float4*)&sh1[f];

    for (int it = 0; it < 8; it++) {
        int d = (blockIdx.x * 8 + it) * 4 + wave;
        float a0 = 0, a1 = 0, a2 = 0, a3 = 0;

        int st = offs[d], n = cnt[d];
        for (int e0 = 0; e0 < n; e0 += 4) {
            int4 ev0 = E[st + e0];
            int4 ev1 = (e0 + 1 < n) ? E[st + e0 + 1] : make_int4(0, 0, 0, 0);
            int4 ev2 = (e0 + 2 < n) ? E[st + e0 + 2] : make_int4(0, 0, 0, 0);
            int4 ev3 = (e0 + 3 < n) ? E[st + e0 + 3] : make_int4(0, 0, 0, 0);
            float w0 = __int_as_float(ev0.y), w1 = __int_as_float(ev1.y);
            float w2 = __int_as_float(ev2.y), w3 = __int_as_float(ev3.y);
            ushort4 v0 = *(const ushort4*)&X1[(size_t)ev0.x * 256 + f];
            ushort4 v1 = *(const ushort4*)&X1[(size_t)ev1.x * 256 + f];
            ushort4 v2 = *(const ushort4*)&X1[(size_t)ev2.x * 256 + f];
            ushort4 v3 = *(const ushort4*)&X1[(size_t)ev3.x * 256 + f];
            const ushort* p0 = (const ushort*)&v0;
            const ushort* p1 = (const ushort*)&v1;
            const ushort* p2 = (const ushort*)&v2;
            const ushort* p3 = (const ushort*)&v3;
            a0 += w0 * fmaxf(bf2f(p0[0]) * sc.x + sh.x, 0.0f)
                + w1 * fmaxf(bf2f(p1[0]) * sc.x + sh.x, 0.0f)
                + w2 * fmaxf(bf2f(p2[0]) * sc.x + sh.x, 0.0f)
                + w3 * fmaxf(bf2f(p3[0]) * sc.x + sh.x, 0.0f);
            a1 += w0 * fmaxf(bf2f(p0[1]) * sc.y + sh.y, 0.0f)
                + w1 * fmaxf(bf2f(p1[1]) * sc.y + sh.y, 0.0f)
                + w2 * fmaxf(bf2f(p2[1]) * sc.y + sh.y, 0.0f)
                + w3 * fmaxf(bf2f(p3[1]) * sc.y + sh.y, 0.0f);
            a2 += w0 * fmaxf(bf2f(p0[2]) * sc.z + sh.z, 0.0f)
                + w1 * fmaxf(bf2f(p1[2]) * sc.z + sh.z, 0.0f)
                + w2 * fmaxf(bf2f(p2[2]) * sc.z + sh.z, 0.0f)
                + w3 * fmaxf(bf2f(p3[2]) * sc.z + sh.z, 0.0f);
            a3 += w0 * fmaxf(bf2f(p0[3]) * sc.w + sh.w, 0.0f)
                + w1 * fmaxf(bf2f(p1[3]) * sc.w + sh.w, 0.0f)
                + w2 * fmaxf(bf2f(p2[3]) * sc.w + sh.w, 0.0f)
                + w3 * fmaxf(bf2f(p3[3]) * sc.w + sh.w, 0.0f);
        }
        *(ushort4*)&G[(size_t)d * 256 + f] =
            make_ushort4(f2bf(a0), f2bf(a1), f2bf(a2), f2bf(a3));
    }
}

// ---------------------------------------------------------------------------
// GEMM final: out[65536,256] f32 = [relu(bn1(X1)) | G] @ W1cat^T + biases + res
// 256x256 tile, 512 thr, grid 256. LDS stride 36.
// ---------------------------------------------------------------------------
__global__ __launch_bounds__(512, 1)
void gemm_final_kernel(const ushort* __restrict__ X1, const ushort* __restrict__ G,
                       const ushort* __restrict__ W1cat,
                       const float* __restrict__ sc1, const float* __restrict__ sh1,
                       const float* __restrict__ biasUi, const float* __restrict__ uj1_b,
                       const float* __restrict__ sumA,
                       const int* __restrict__ colof, const float* __restrict__ valof,
                       const ushort* __restrict__ XW,
                       float* __restrict__ out)
{
    __shared__ ushort As[256 * LSTR];
    __shared__ ushort Bs[256 * LSTR];
    __shared__ float s_sc[256], s_sh[256];

    const int tid = threadIdx.x;
    const int tM = blockIdx.x * 256;

    if (tid < 256) { s_sc[tid] = sc1[tid]; s_sh[tid] = sh1[tid]; }
    __syncthreads();

    const int lane = tid & 63;
    const int wave = tid >> 6;
    const int wm = wave >> 1, wn = wave & 1;    // wave tile 64 rows x 128 cols
    const int lr = lane & 15, lg = lane >> 4;

    f32x4 acc[4][8] = {};

    for (int k0 = 0; k0 < 512; k0 += 32) {
#pragma unroll
        for (int i = 0; i < 2; i++) {
            int idx = tid + i * 512;
            int row = idx >> 2, u = idx & 3;
            ushort h[8];
            if (k0 < 256) {
                *(uint4*)h = *(const uint4*)&X1[(size_t)(tM + row) * 256 + k0 + u * 8];
#pragma unroll
                for (int j = 0; j < 8; j++) {
                    int c = k0 + u * 8 + j;
                    h[j] = f2bf(fmaxf(bf2f(h[j]) * s_sc[c] + s_sh[c], 0.0f));
                }
            } else {
                *(uint4*)h = *(const uint4*)&G[(size_t)(tM + row) * 256 + (k0 - 256) + u * 8];
            }
            *(uint4*)&As[row * LSTR + u * 8] = *(uint4*)h;
        }
#pragma unroll
        for (int i = 0; i < 2; i++) {
            int idx = tid + i * 512;
            int row = idx >> 2, u = idx & 3;
            *(uint4*)&Bs[row * LSTR + u * 8] =
                *(const uint4*)&W1cat[(size_t)row * 512 + k0 + u * 8];
        }
        __syncthreads();

        bfrag af[4], bfv[8];
#pragma unroll
        for (int mm = 0; mm < 4; mm++) {
            int row = wm * 64 + mm * 16 + lr;
            af[mm] = *(const bfrag*)&As[row * LSTR + lg * 8];
        }
#pragma unroll
        for (int nn = 0; nn < 8; nn++) {
            int row = wn * 128 + nn * 16 + lr;
            bfv[nn] = *(const bfrag*)&Bs[row * LSTR + lg * 8];
        }
#pragma unroll
        for (int mm = 0; mm < 4; mm++)
#pragma unroll
            for (int nn = 0; nn < 8; nn++)
                acc[mm][nn] = __builtin_amdgcn_mfma_f32_16x16x32_bf16(af[mm], bfv[nn], acc[mm][nn], 0, 0, 0);
        __syncthreads();
    }

    float bUi[8], bUj[8];
#pragma unroll
    for (int nn = 0; nn < 8; nn++) {
        int col = wn * 128 + nn * 16 + lr;
        bUi[nn] = biasUi[col];
        bUj[nn] = uj1_b[col];
    }
#pragma unroll
    for (int mm = 0; mm < 4; mm++) {
#pragma unroll
        for (int r = 0; r < 4; r++) {
            int row = tM + wm * 64 + mm * 16 + lg * 4 + r;
            int c = colof[row];
            float s = valof[row];
            float sA = sumA[row];
#pragma unroll
            for (int nn = 0; nn < 8; nn++) {
                int col = wn * 128 + nn * 16 + lr;
                float v = acc[mm][nn][r] + bUi[nn] + sA * bUj[nn]
                        + s * bf2f(XW[(size_t)c * 256 + col]);
                out[(size_t)row * 256 + col] = v;
            }
        }
    }
}

// ---------------------------------------------------------------------------
// Host launcher
// ---------------------------------------------------------------------------
extern "C" void kernel_launch(void* const* d_in, const int* in_sizes, int n_in,
                              void* d_out, int out_size, void* d_ws, size_t ws_size,
                              hipStream_t stream)
{
    const float* x      = (const float*)d_in[0];
    const int*   up_row = (const int*)  d_in[1];
    const int*   up_col = (const int*)  d_in[2];
    const float* up_val = (const float*)d_in[3];
    const int*   e_src  = (const int*)  d_in[4];
    const int*   e_dst  = (const int*)  d_in[5];
    const float* adjv   = (const float*)d_in[6];
    const float* W_res  = (const float*)d_in[7];
    const float* b_res  = (const float*)d_in[8];
    const float* bn0_g  = (const float*)d_in[9];
    const float* bn0_b  = (const float*)d_in[10];
    const float* bn1_g  = (const float*)d_in[11];
    const float* bn1_b  = (const float*)d_in[12];
    const float* Ui0_W  = (const float*)d_in[13];
    const float* Ui0_b  = (const float*)d_in[14];
    const float* Uj0_W  = (const float*)d_in[15];
    const float* Uj0_b  = (const float*)d_in[16];
    const float* Ui1_W  = (const float*)d_in[17];
    const float* Ui1_b  = (const float*)d_in[18];
    const float* Uj1_W  = (const float*)d_in[19];
    const float* Uj1_b  = (const float*)d_in[20];

    float* out = (float*)d_out;

    // ---- workspace layout ----
    char* ws = (char*)d_ws;
    size_t off = 0;
    auto alloc = [&](size_t bytes) -> char* {
        char* p = ws + off;
        off = (off + bytes + 255) & ~(size_t)255;
        return p;
    };
    ushort* XW    = (ushort*)alloc((size_t)V_PREV * F_OUT * 2);   // 8.4 MB
    ushort* XNJ   = (ushort*)alloc((size_t)V_PREV * F_OUT * 2);   // 8.4 MB
    ushort* XNI   = (ushort*)alloc((size_t)V_PREV * F_OUT * 2);   // 8.4 MB
    ushort* XBF   = (ushort*)alloc((size_t)V_PREV * F_IN * 2);    // 16.8 MB
    ushort* X1    = (ushort*)alloc((size_t)V_NEXT * F_OUT * 2);   // 33.6 MB
    ushort* G     = (ushort*)alloc((size_t)V_NEXT * F_OUT * 2);   // 33.6 MB
    // --- zeroed region (memsetAsync): cnt, psum1s, psq1s = 98304 ints ---
    int*    cnt   = (int*)   alloc(V_NEXT * 4);                   // 256 KB
    float*  psum1s= (float*) alloc(64 * 256 * 4);                 // 64 KB
    float*  psq1s = (float*) alloc(64 * 256 * 4);                 // 64 KB
    float*  sumA  = (float*) alloc(V_NEXT * 4);
    int*    offs  = (int*)   alloc(V_NEXT * 4);
    int*    cursor= (int*)   alloc(V_NEXT * 4);
    int*    bsum  = (int*)   alloc(256 * 4);
    int4*   E     = (int4*)  alloc((size_t)N_EDGE * 16);          // 8.4 MB
    int*    colof = (int*)   alloc(V_NEXT * 4);
    float*  valof = (float*) alloc(V_NEXT * 4);
    ushort* WresT = (ushort*)alloc(256 * 512 * 2);
    ushort* W0t   = (ushort*)alloc(512 * 512 * 2);
    ushort* W1cat = (ushort*)alloc(256 * 512 * 2);
    float*  biasUi= (float*) alloc(256 * 4);
    float*  psum0 = (float*) alloc(512 * 512 * 4);                // 1 MB
    float*  psq0  = (float*) alloc(512 * 512 * 4);                // 1 MB
    float*  sc0   = (float*) alloc(512 * 4);
    float*  sh0   = (float*) alloc(512 * 4);
    float*  sc1   = (float*) alloc(256 * 4);
    float*  sh1   = (float*) alloc(256 * 4);
    (void)ws_size; (void)in_sizes; (void)n_in; (void)out_size;

    // ---- K0: zero cnt + psum1s + psq1s (contiguous) ----
    hipMemsetAsync(cnt, 0, (size_t)98304 * 4, stream);

    // ---- K1: mega prep: weights + up-invert + hist + bn0 partials + XBF ----
    mega_prep_kernel<<<3840, 256, 0, stream>>>(W_res, Ui0_W, Uj0_W, Ui1_W, Uj1_W,
                                               Ui1_b, b_res,
                                               up_row, up_col, up_val,
                                               e_dst, x,
                                               WresT, W0t, W1cat, biasUi,
                                               colof, valof, cnt, psum0, psq0, XBF);

    // ---- K2: block scan ----
    scan_block_kernel<<<256, 256, 0, stream>>>(cnt, offs, bsum);

    // ---- K3: offset add + bn0 finish ----
    add_offs_bnfin_kernel<<<384, 256, 0, stream>>>(offs, bsum, cursor,
                                                   psum0, psq0, bn0_g, bn0_b, sc0, sh0);

    // ---- K4: GEMM0 (bf16 A, blocks 0..767) + edge fill (768..2815) ----
    fill_gemm0_kernel<<<2816, 256, 0, stream>>>(e_src, e_dst, adjv, colof, valof,
                                                cursor, E,
                                                XBF, WresT, W0t, sc0, sh0,
                                                XW, XNJ, XNI);

    // ---- K5: ECC layer 0 aggregation + sumA + bn1 stats (persistent) ----
    gather0_kernel<<<2048, 256, 0, stream>>>(offs, cnt, E, colof, valof,
                                             XNJ, XNI, Ui0_b, Uj0_b,
                                             X1, sumA, psum1s, psq1s);

    // ---- K6: bn1 finish ----
    bn_finish_kernel<<<64, 256, 0, stream>>>(psum1s, psq1s, 64, 256, 1.0f / V_NEXT,
                                             bn1_g, bn1_b, sc1, sh1);

    // ---- K7: ECC layer 1 aggregation (commuted, persistent) ----
    gather1G_kernel<<<2048, 256, 0, stream>>>(offs, cnt, E, X1, sc1, sh1, G);

    // ---- K8: final GEMM: out = [H1|G] @ W1cat + biases + residual ----
    gemm_final_kernel<<<256, 512, 0, stream>>>(X1, G, W1cat, sc1, sh1,
                                               biasUi, Uj1_b, sumA,
                                               colof, valof, XW, out);
}

// Round 19
// 231.363 us; speedup vs baseline: 1.0393x; 1.0014x over previous
//
#include <hip/hip_runtime.h>

// ---------------------------------------------------------------------------
// Problem constants
// ---------------------------------------------------------------------------
#define V_PREV 16384
#define V_NEXT 65536
#define F_IN   512
#define F_OUT  256
#define NNZ_UP 65536
#define N_EDGE 524288

using f32x4 = __attribute__((ext_vector_type(4))) float;
using bfrag = __attribute__((ext_vector_type(8))) short;   // 8 x bf16

#define LSTR  36   // 32-col LDS row stride (shorts): 18*row mod 32 -> <=2-way
#define LSTR2 72   // 64-col LDS row stride (shorts): 36*row mod 32 -> <=2-way

__device__ __forceinline__ ushort f2bf(float f) {
    union { float f; unsigned u; } v; v.f = f;
    unsigned r = (v.u + 0x7FFFu + ((v.u >> 16) & 1u)) >> 16;
    return (ushort)r;
}
__device__ __forceinline__ float bf2f(ushort h) {
    union { unsigned u; float f; } v; v.u = ((unsigned)h) << 16; return v.f;
}

// ---------------------------------------------------------------------------
// Mega K1: weight prep (0..1023) + invert_up (1024..1279)
//        + hist cnt (1280..3327) + bn0_part + XBF=bf16(x) (3328..3839)
// ---------------------------------------------------------------------------
__global__ void mega_prep_kernel(const float* __restrict__ Wres,
                                 const float* __restrict__ Ui0W, const float* __restrict__ Uj0W,
                                 const float* __restrict__ Ui1W, const float* __restrict__ Uj1W,
                                 const float* __restrict__ Ui1b, const float* __restrict__ bres,
                                 const int* __restrict__ up_row, const int* __restrict__ up_col,
                                 const float* __restrict__ up_val,
                                 const int* __restrict__ dst,
                                 const float* __restrict__ x,
                                 ushort* __restrict__ WresT, ushort* __restrict__ W0t,
                                 ushort* __restrict__ W1cat, float* __restrict__ biasUi,
                                 int* __restrict__ colof, float* __restrict__ valof,
                                 int* __restrict__ cnt,
                                 float* __restrict__ psum0, float* __restrict__ psq0,
                                 ushort* __restrict__ XBF)
{
    int b = blockIdx.x, t = threadIdx.x;
    if (b < 1024) {
        int i = b * 256 + t;                      // 0 .. 262143
        if (i < 256 * 512) {
            int n = i / 512, k = i % 512;
            WresT[i] = f2bf(Wres[k * 256 + n]);
            W1cat[i] = f2bf(k < 256 ? Ui1W[k * 256 + n] : Uj1W[(k - 256) * 256 + n]);
        }
        {
            int n = i / 512, k = i % 512;
            W0t[i] = f2bf(n < 256 ? Uj0W[k * 256 + n] : Ui0W[k * 256 + (n - 256)]);
        }
        if (i < 256) biasUi[i] = Ui1b[i] + bres[i];
    } else if (b < 1280) {
        int k = (b - 1024) * 256 + t;             // 0 .. 65535
        int r = up_row[k];
        colof[r] = up_col[k];
        valof[r] = up_val[k];
    } else if (b < 3328) {
        int e = (b - 1280) * 256 + t;             // 0 .. 524287
        atomicAdd(&cnt[dst[e]], 1);
    } else {
        int blk = b - 3328;                        // 0..511, 32 rows each
        float s0 = 0, s1 = 0, q0 = 0, q1 = 0;
        for (int r = 0; r < 32; r++) {
            size_t base = ((size_t)blk * 32 + r) * 512;
            float a = x[base + t], bb = x[base + t + 256];
            s0 += a; q0 += a * a; s1 += bb; q1 += bb * bb;
            XBF[base + t]       = f2bf(a);
            XBF[base + t + 256] = f2bf(bb);
        }
        psum0[blk * 512 + t] = s0; psum0[blk * 512 + t + 256] = s1;
        psq0 [blk * 512 + t] = q0; psq0 [blk * 512 + t + 256] = q1;
    }
}

// ---------------------------------------------------------------------------
// CSR scan
// ---------------------------------------------------------------------------
__global__ void scan_block_kernel(const int* __restrict__ cnt, int* __restrict__ offs,
                                  int* __restrict__ bsum)
{
    __shared__ int buf[2][256];
    int t = threadIdx.x;
    int i = blockIdx.x * 256 + t;
    int v = cnt[i];
    int p = 0;
    buf[0][t] = v;
    __syncthreads();
    for (int d = 1; d < 256; d <<= 1) {
        int nv = buf[p][t] + ((t >= d) ? buf[p][t - d] : 0);
        buf[p ^ 1][t] = nv;
        p ^= 1;
        __syncthreads();
    }
    int incl = buf[p][t];
    offs[i] = incl - v;
    if (t == 255) bsum[blockIdx.x] = incl;
}

// Fat: add_offs2 (0..255) + bn0 finish (256..383, nblocks=512)
__global__ void add_offs_bnfin_kernel(int* __restrict__ offs, const int* __restrict__ bsum,
                                      int* __restrict__ cursor,
                                      const float* __restrict__ psum0, const float* __restrict__ psq0,
                                      const float* __restrict__ g0, const float* __restrict__ b0,
                                      float* __restrict__ sc0, float* __restrict__ sh0)
{
    int b = blockIdx.x, t = threadIdx.x;
    if (b < 256) {
        __shared__ int buf[2][256];
        int v = bsum[t];
        int p = 0;
        buf[0][t] = v;
        __syncthreads();
        for (int d = 1; d < 256; d <<= 1) {
            int nv = buf[p][t] + ((t >= d) ? buf[p][t - d] : 0);
            buf[p ^ 1][t] = nv;
            p ^= 1;
            __syncthreads();
        }
        int excl = buf[p][b] - bsum[b];
        int i = b * 256 + t;
        int o = offs[i] + excl;
        offs[i] = o;
        cursor[i] = o;
    } else {
        int vb = b - 256;                          // 0..127
        int gw = (vb * 256 + t) >> 6;              // channel 0..511
        int lane = t & 63;
        float s = 0, q = 0;
        for (int i = lane; i < 512; i += 64) {
            s += psum0[(size_t)i * 512 + gw];
            q += psq0 [(size_t)i * 512 + gw];
        }
#pragma unroll
        for (int d = 32; d > 0; d >>= 1) {
            s += __shfl_xor(s, d);
            q += __shfl_xor(q, d);
        }
        if (lane == 0) {
            float m = s * (1.0f / V_PREV);
            float v = q * (1.0f / V_PREV) - m * m;
            float r = rsqrtf(v + 1e-5f);
            float scale = r * g0[gw];
            sc0[gw] = scale;
            sh0[gw] = b0[gw] - m * scale;
        }
    }
}

// bn1 finish (standalone)
__global__ void bn_finish_kernel(const float* __restrict__ psum, const float* __restrict__ psq,
                                 int nblocks, int C, float invN,
                                 const float* __restrict__ g, const float* __restrict__ b,
                                 float* __restrict__ sc, float* __restrict__ sh)
{
    int gw = (blockIdx.x * blockDim.x + threadIdx.x) >> 6;
    int lane = threadIdx.x & 63;
    if (gw >= C) return;
    float s = 0, q = 0;
    for (int i = lane; i < nblocks; i += 64) {
        s += psum[(size_t)i * C + gw];
        q += psq [(size_t)i * C + gw];
    }
#pragma unroll
    for (int d = 32; d > 0; d >>= 1) {
        s += __shfl_xor(s, d);
        q += __shfl_xor(q, d);
    }
    if (lane == 0) {
        float m = s * invN;
        float v = q * invN - m * m;
        float r = rsqrtf(v + 1e-5f);
        float scale = r * g[gw];
        sc[gw] = scale;
        sh[gw] = b[gw] - m * scale;
    }
}

// ---------------------------------------------------------------------------
// Fat: gemm0 FIRST (0..767, XCD-grouped, BK=64) + fill (768..2815)
// gemm0: A = XBF; bx 0,1: XW = XBF@WresT; 2,3: XNJ = bn-relu(XBF)@Uj0; 4,5: XNI
//   BK=64: 8 K-iterations, 32 MFMA per barrier-pair. LDS stride 72 (<=2-way).
// fill: E[p] = {srcA, valA, src0=colof[s], val0=a*valof[s]}  (one 16B store)
// ---------------------------------------------------------------------------
__global__ __launch_bounds__(256)
void fill_gemm0_kernel(const int* __restrict__ src, const int* __restrict__ dst,
                       const float* __restrict__ adjv,
                       const int* __restrict__ colof, const float* __restrict__ valof,
                       int* __restrict__ cursor, int4* __restrict__ E,
                       const ushort* __restrict__ XBF,
                       const ushort* __restrict__ WresT, const ushort* __restrict__ W0t,
                       const float* __restrict__ sc0, const float* __restrict__ sh0,
                       ushort* __restrict__ XW, ushort* __restrict__ XNJ,
                       ushort* __restrict__ XNI)
{
    __shared__ ushort As[128 * LSTR2];
    __shared__ ushort Bs[128 * LSTR2];
    __shared__ float s_sc[512], s_sh[512];

    const int tid = threadIdx.x;
    if (blockIdx.x >= 768) {
        int e = (blockIdx.x - 768) * 256 + tid;
        int d = dst[e];
        int s = src[e];
        float a = adjv[e];
        int p = atomicAdd(&cursor[d], 1);
        int4 v;
        v.x = s;
        v.y = __float_as_int(a);
        v.z = colof[s];
        v.w = __float_as_int(a * valof[s]);
        E[p] = v;
        return;
    }

    const int id   = blockIdx.x;               // 0..767
    const int xcd  = id & 7;
    const int rest = id >> 3;
    const int slot = rest / 6;
    const int bx   = rest - slot * 6;
    const int by   = slot * 8 + xcd;

    const bool bnmode = bx >= 2;
    const ushort* Bt = bnmode ? W0t : WresT;
    const int btrow = bnmode ? (bx - 2) * 128 : bx * 128;
    ushort* Cout = (bx < 2) ? XW : (bx < 4 ? XNJ : XNI);
    const int colbase = (bx & 1) * 128;
    const int tM = by * 128;

    for (int i = tid; i < 512; i += 256) { s_sc[i] = sc0[i]; s_sh[i] = sh0[i]; }
    __syncthreads();

    const int lane = tid & 63;
    const int wave = tid >> 6;
    const int wm = wave >> 1, wn = wave & 1;
    const int lr = lane & 15, lg = lane >> 4;

    f32x4 acc[4][4] = {};

    for (int k0 = 0; k0 < 512; k0 += 64) {
        // --- A stage: 128 rows x 8 units, 4 per thread, optional bn+relu ---
#pragma unroll
        for (int i = 0; i < 4; i++) {
            int idx = tid + i * 256;            // 0..1023
            int row = idx >> 3, u = idx & 7;
            ushort h[8];
            *(uint4*)h = *(const uint4*)&XBF[(size_t)(tM + row) * 512 + k0 + u * 8];
            if (bnmode) {
#pragma unroll
                for (int j = 0; j < 8; j++) {
                    int c = k0 + u * 8 + j;
                    h[j] = f2bf(fmaxf(bf2f(h[j]) * s_sc[c] + s_sh[c], 0.0f));
                }
            }
            *(uint4*)&As[row * LSTR2 + u * 8] = *(uint4*)h;
        }
        // --- B stage: 128 rows x 8 units, 4 per thread ---
#pragma unroll
        for (int i = 0; i < 4; i++) {
            int idx = tid + i * 256;
            int row = idx >> 3, u = idx & 7;
            *(uint4*)&Bs[row * LSTR2 + u * 8] =
                *(const uint4*)&Bt[(size_t)(btrow + row) * 512 + k0 + u * 8];
        }
        __syncthreads();

#pragma unroll
        for (int ks = 0; ks < 2; ks++) {
            bfrag af[4], bfv[4];
#pragma unroll
            for (int mm = 0; mm < 4; mm++) {
                int row = wm * 64 + mm * 16 + lr;
                af[mm] = *(const bfrag*)&As[row * LSTR2 + (ks * 4 + lg) * 8];
            }
#pragma unroll
            for (int nn = 0; nn < 4; nn++) {
                int row = wn * 64 + nn * 16 + lr;
                bfv[nn] = *(const bfrag*)&Bs[row * LSTR2 + (ks * 4 + lg) * 8];
            }
#pragma unroll
            for (int mm = 0; mm < 4; mm++)
#pragma unroll
                for (int nn = 0; nn < 4; nn++)
                    acc[mm][nn] = __builtin_amdgcn_mfma_f32_16x16x32_bf16(af[mm], bfv[nn], acc[mm][nn], 0, 0, 0);
        }
        __syncthreads();
    }

#pragma unroll
    for (int mm = 0; mm < 4; mm++)
#pragma unroll
        for (int nn = 0; nn < 4; nn++)
#pragma unroll
            for (int r = 0; r < 4; r++) {
                int row = tM + wm * 64 + mm * 16 + lg * 4 + r;
                int col = colbase + wn * 64 + nn * 16 + lr;
                Cout[(size_t)row * 256 + col] = f2bf(acc[mm][nn][r]);
            }
}

// ---------------------------------------------------------------------------
// Gather layer 0, persistent (2048 blocks x 8 iters), 4-wide batched loads.
// sumA computed on the fly; bn1 stats in registers.
// ---------------------------------------------------------------------------
__global__ __launch_bounds__(256)
void gather0_kernel(const int* __restrict__ offs, const int* __restrict__ cnt,
                    const int4* __restrict__ E,
                    const int* __restrict__ colof, const float* __restrict__ valof,
                    const ushort* __restrict__ XNJ, const ushort* __restrict__ XNI,
                    const float* __restrict__ ui_b, const float* __restrict__ uj_b,
                    ushort* __restrict__ X1, float* __restrict__ sumA,
                    float* __restrict__ psum1s, float* __restrict__ psq1s)
{
    __shared__ float redS[4][256];
    __shared__ float redQ[4][256];

    int wave = threadIdx.x >> 6;
    int lane = threadIdx.x & 63;
    int f = lane * 4;
    float ub0 = ui_b[f + 0], ub1 = ui_b[f + 1], ub2 = ui_b[f + 2], ub3 = ui_b[f + 3];
    float jb0 = uj_b[f + 0], jb1 = uj_b[f + 1], jb2 = uj_b[f + 2], jb3 = uj_b[f + 3];
    float ss0 = 0, ss1 = 0, ss2 = 0, ss3 = 0;
    float qq0 = 0, qq1 = 0, qq2 = 0, qq3 = 0;

    for (int it = 0; it < 8; it++) {
        int d = (blockIdx.x * 8 + it) * 4 + wave;
        int c = colof[d];
        float s = valof[d];
        ushort4 u = *(const ushort4*)&XNI[(size_t)c * 256 + f];
        const ushort* up = (const ushort*)&u;
        float a0 = ub0 + s * bf2f(up[0]);
        float a1 = ub1 + s * bf2f(up[1]);
        float a2 = ub2 + s * bf2f(up[2]);
        float a3 = ub3 + s * bf2f(up[3]);
        float sA = 0;

        int st = offs[d], n = cnt[d];
        for (int e0 = 0; e0 < n; e0 += 4) {
            int4 ev0 = E[st + e0];
            int4 ev1 = (e0 + 1 < n) ? E[st + e0 + 1] : make_int4(0, 0, 0, 0);
            int4 ev2 = (e0 + 2 < n) ? E[st + e0 + 2] : make_int4(0, 0, 0, 0);
            int4 ev3 = (e0 + 3 < n) ? E[st + e0 + 3] : make_int4(0, 0, 0, 0);
            float w0 = __int_as_float(ev0.w), w1 = __int_as_float(ev1.w);
            float w2 = __int_as_float(ev2.w), w3 = __int_as_float(ev3.w);
            sA += __int_as_float(ev0.y) + __int_as_float(ev1.y)
                + __int_as_float(ev2.y) + __int_as_float(ev3.y);
            ushort4 v0 = *(const ushort4*)&XNJ[(size_t)ev0.z * 256 + f];
            ushort4 v1 = *(const ushort4*)&XNJ[(size_t)ev1.z * 256 + f];
            ushort4 v2 = *(const ushort4*)&XNJ[(size_t)ev2.z * 256 + f];
            ushort4 v3 = *(const ushort4*)&XNJ[(size_t)ev3.z * 256 + f];
            const ushort* p0 = (const ushort*)&v0;
            const ushort* p1 = (const ushort*)&v1;
            const ushort* p2 = (const ushort*)&v2;
            const ushort* p3 = (const ushort*)&v3;
            a0 += w0 * bf2f(p0[0]) + w1 * bf2f(p1[0]) + w2 * bf2f(p2[0]) + w3 * bf2f(p3[0]);
            a1 += w0 * bf2f(p0[1]) + w1 * bf2f(p1[1]) + w2 * bf2f(p2[1]) + w3 * bf2f(p3[1]);
            a2 += w0 * bf2f(p0[2]) + w1 * bf2f(p1[2]) + w2 * bf2f(p2[2]) + w3 * bf2f(p3[2]);
            a3 += w0 * bf2f(p0[3]) + w1 * bf2f(p1[3]) + w2 * bf2f(p2[3]) + w3 * bf2f(p3[3]);
        }
        a0 += sA * jb0; a1 += sA * jb1; a2 += sA * jb2; a3 += sA * jb3;
        *(ushort4*)&X1[(size_t)d * 256 + f] =
            make_ushort4(f2bf(a0), f2bf(a1), f2bf(a2), f2bf(a3));
        if (lane == 0) sumA[d] = sA;
        ss0 += a0; ss1 += a1; ss2 += a2; ss3 += a3;
        qq0 += a0 * a0; qq1 += a1 * a1; qq2 += a2 * a2; qq3 += a3 * a3;
    }

    redS[wave][f + 0] = ss0; redS[wave][f + 1] = ss1;
    redS[wave][f + 2] = ss2; redS[wave][f + 3] = ss3;
    redQ[wave][f + 0] = qq0; redQ[wave][f + 1] = qq1;
    redQ[wave][f + 2] = qq2; redQ[wave][f + 3] = qq3;
    __syncthreads();
    int t = threadIdx.x;   // channel
    float ssum = redS[0][t] + redS[1][t] + redS[2][t] + redS[3][t];
    float sq   = redQ[0][t] + redQ[1][t] + redQ[2][t] + redQ[3][t];
    int slab = (blockIdx.x & 63) * 256 + t;
    atomicAdd(&psum1s[slab], ssum);
    atomicAdd(&psq1s[slab], sq);
}

// ---------------------------------------------------------------------------
// Gather layer 1 (pre-GEMM, bn1+relu folded), persistent (2048 blocks x 8):
//   G[d] = sum_e valA * relu(sc1*X1[srcA] + sh1)     (bf16 out)
// ---------------------------------------------------------------------------
__global__ __launch_bounds__(256)
void gather1G_kernel(const int* __restrict__ offs, const int* __restrict__ cnt,
                     const int4* __restrict__ E,
                     const ushort* __restrict__ X1,
                     const float* __restrict__ sc1, const float* __restrict__ sh1,
                     ushort* __restrict__ G)
{
    int wave = threadIdx.x >> 6;
    int f = (threadIdx.x & 63) * 4;
    float4 sc = *(const float4*)&sc1[f];
    float4 sh = *(const float4*)&sh1[f];

    for (int it = 0; it < 8; it++) {
        int d = (blockIdx.x * 8 + it) * 4 + wave;
        float a0 = 0, a1 = 0, a2 = 0, a3 = 0;

        int st = offs[d], n = cnt[d];
        for (int e0 = 0; e0 < n; e0 += 4) {
            int4 ev0 = E[st + e0];
            int4 ev1 = (e0 + 1 < n) ? E[st + e0 + 1] : make_int4(0, 0, 0, 0);
            int4 ev2 = (e0 + 2 < n) ? E[st + e0 + 2] : make_int4(0, 0, 0, 0);
            int4 ev3 = (e0 + 3 < n) ? E[st + e0 + 3] : make_int4(0, 0, 0, 0);
            float w0 = __int_as_float(ev0.y), w1 = __int_as_float(ev1.y);
            float w2 = __int_as_float(ev2.y), w3 = __int_as_float(ev3.y);
            ushort4 v0 = *(const ushort4*)&X1[(size_t)ev0.x * 256 + f];
            ushort4 v1 = *(const ushort4*)&X1[(size_t)ev1.x * 256 + f];
            ushort4 v2 = *(const ushort4*)&X1[(size_t)ev2.x * 256 + f];
            ushort4 v3 = *(const ushort4*)&X1[(size_t)ev3.x * 256 + f];
            const ushort* p0 = (const ushort*)&v0;
            const ushort* p1 = (const ushort*)&v1;
            const ushort* p2 = (const ushort*)&v2;
            const ushort* p3 = (const ushort*)&v3;
            a0 += w0 * fmaxf(bf2f(p0[0]) * sc.x + sh.x, 0.0f)
                + w1 * fmaxf(bf2f(p1[0]) * sc.x + sh.x, 0.0f)
                + w2 * fmaxf(bf2f(p2[0]) * sc.x + sh.x, 0.0f)
                + w3 * fmaxf(bf2f(p3[0]) * sc.x + sh.x, 0.0f);
            a1 += w0 * fmaxf(bf2f(p0[1]) * sc.y + sh.y, 0.0f)
                + w1 * fmaxf(bf2f(p1[1]) * sc.y + sh.y, 0.0f)
                + w2 * fmaxf(bf2f(p2[1]) * sc.y + sh.y, 0.0f)
                + w3 * fmaxf(bf2f(p3[1]) * sc.y + sh.y, 0.0f);
            a2 += w0 * fmaxf(bf2f(p0[2]) * sc.z + sh.z, 0.0f)
                + w1 * fmaxf(bf2f(p1[2]) * sc.z + sh.z, 0.0f)
                + w2 * fmaxf(bf2f(p2[2]) * sc.z + sh.z, 0.0f)
                + w3 * fmaxf(bf2f(p3[2]) * sc.z + sh.z, 0.0f);
            a3 += w0 * fmaxf(bf2f(p0[3]) * sc.w + sh.w, 0.0f)
                + w1 * fmaxf(bf2f(p1[3]) * sc.w + sh.w, 0.0f)
                + w2 * fmaxf(bf2f(p2[3]) * sc.w + sh.w, 0.0f)
                + w3 * fmaxf(bf2f(p3[3]) * sc.w + sh.w, 0.0f);
        }
        *(ushort4*)&G[(size_t)d * 256 + f] =
            make_ushort4(f2bf(a0), f2bf(a1), f2bf(a2), f2bf(a3));
    }
}

// ---------------------------------------------------------------------------
// GEMM final: out[65536,256] f32 = [relu(bn1(X1)) | G] @ W1cat^T + biases + res
// 256x256 tile, 512 thr, grid 256. LDS stride 36.
// ---------------------------------------------------------------------------
__global__ __launch_bounds__(512, 1)
void gemm_final_kernel(const ushort* __restrict__ X1, const ushort* __restrict__ G,
                       const ushort* __restrict__ W1cat,
                       const float* __restrict__ sc1, const float* __restrict__ sh1,
                       const float* __restrict__ biasUi, const float* __restrict__ uj1_b,
                       const float* __restrict__ sumA,
                       const int* __restrict__ colof, const float* __restrict__ valof,
                       const ushort* __restrict__ XW,
                       float* __restrict__ out)
{
    __shared__ ushort As[256 * LSTR];
    __shared__ ushort Bs[256 * LSTR];
    __shared__ float s_sc[256], s_sh[256];

    const int tid = threadIdx.x;
    const int tM = blockIdx.x * 256;

    if (tid < 256) { s_sc[tid] = sc1[tid]; s_sh[tid] = sh1[tid]; }
    __syncthreads();

    const int lane = tid & 63;
    const int wave = tid >> 6;
    const int wm = wave >> 1, wn = wave & 1;    // wave tile 64 rows x 128 cols
    const int lr = lane & 15, lg = lane >> 4;

    f32x4 acc[4][8] = {};

    for (int k0 = 0; k0 < 512; k0 += 32) {
#pragma unroll
        for (int i = 0; i < 2; i++) {
            int idx = tid + i * 512;
            int row = idx >> 2, u = idx & 3;
            ushort h[8];
            if (k0 < 256) {
                *(uint4*)h = *(const uint4*)&X1[(size_t)(tM + row) * 256 + k0 + u * 8];
#pragma unroll
                for (int j = 0; j < 8; j++) {
                    int c = k0 + u * 8 + j;
                    h[j] = f2bf(fmaxf(bf2f(h[j]) * s_sc[c] + s_sh[c], 0.0f));
                }
            } else {
                *(uint4*)h = *(const uint4*)&G[(size_t)(tM + row) * 256 + (k0 - 256) + u * 8];
            }
            *(uint4*)&As[row * LSTR + u * 8] = *(uint4*)h;
        }
#pragma unroll
        for (int i = 0; i < 2; i++) {
            int idx = tid + i * 512;
            int row = idx >> 2, u = idx & 3;
            *(uint4*)&Bs[row * LSTR + u * 8] =
                *(const uint4*)&W1cat[(size_t)row * 512 + k0 + u * 8];
        }
        __syncthreads();

        bfrag af[4], bfv[8];
#pragma unroll
        for (int mm = 0; mm < 4; mm++) {
            int row = wm * 64 + mm * 16 + lr;
            af[mm] = *(const bfrag*)&As[row * LSTR + lg * 8];
        }
#pragma unroll
        for (int nn = 0; nn < 8; nn++) {
            int row = wn * 128 + nn * 16 + lr;
            bfv[nn] = *(const bfrag*)&Bs[row * LSTR + lg * 8];
        }
#pragma unroll
        for (int mm = 0; mm < 4; mm++)
#pragma unroll
            for (int nn = 0; nn < 8; nn++)
                acc[mm][nn] = __builtin_amdgcn_mfma_f32_16x16x32_bf16(af[mm], bfv[nn], acc[mm][nn], 0, 0, 0);
        __syncthreads();
    }

    float bUi[8], bUj[8];
#pragma unroll
    for (int nn = 0; nn < 8; nn++) {
        int col = wn * 128 + nn * 16 + lr;
        bUi[nn] = biasUi[col];
        bUj[nn] = uj1_b[col];
    }
#pragma unroll
    for (int mm = 0; mm < 4; mm++) {
#pragma unroll
        for (int r = 0; r < 4; r++) {
            int row = tM + wm * 64 + mm * 16 + lg * 4 + r;
            int c = colof[row];
            float s = valof[row];
            float sA = sumA[row];
#pragma unroll
            for (int nn = 0; nn < 8; nn++) {
                int col = wn * 128 + nn * 16 + lr;
                float v = acc[mm][nn][r] + bUi[nn] + sA * bUj[nn]
                        + s * bf2f(XW[(size_t)c * 256 + col]);
                out[(size_t)row * 256 + col] = v;
            }
        }
    }
}

// ---------------------------------------------------------------------------
// Host launcher
// ---------------------------------------------------------------------------
extern "C" void kernel_launch(void* const* d_in, const int* in_sizes, int n_in,
                              void* d_out, int out_size, void* d_ws, size_t ws_size,
                              hipStream_t stream)
{
    const float* x      = (const float*)d_in[0];
    const int*   up_row = (const int*)  d_in[1];
    const int*   up_col = (const int*)  d_in[2];
    const float* up_val = (const float*)d_in[3];
    const int*   e_src  = (const int*)  d_in[4];
    const int*   e_dst  = (const int*)  d_in[5];
    const float* adjv   = (const float*)d_in[6];
    const float* W_res  = (const float*)d_in[7];
    const float* b_res  = (const float*)d_in[8];
    const float* bn0_g  = (const float*)d_in[9];
    const float* bn0_b  = (const float*)d_in[10];
    const float* bn1_g  = (const float*)d_in[11];
    const float* bn1_b  = (const float*)d_in[12];
    const float* Ui0_W  = (const float*)d_in[13];
    const float* Ui0_b  = (const float*)d_in[14];
    const float* Uj0_W  = (const float*)d_in[15];
    const float* Uj0_b  = (const float*)d_in[16];
    const float* Ui1_W  = (const float*)d_in[17];
    const float* Ui1_b  = (const float*)d_in[18];
    const float* Uj1_W  = (const float*)d_in[19];
    const float* Uj1_b  = (const float*)d_in[20];

    float* out = (float*)d_out;

    // ---- workspace layout ----
    char* ws = (char*)d_ws;
    size_t off = 0;
    auto alloc = [&](size_t bytes) -> char* {
        char* p = ws + off;
        off = (off + bytes + 255) & ~(size_t)255;
        return p;
    };
    ushort* XW    = (ushort*)alloc((size_t)V_PREV * F_OUT * 2);   // 8.4 MB
    ushort* XNJ   = (ushort*)alloc((size_t)V_PREV * F_OUT * 2);   // 8.4 MB
    ushort* XNI   = (ushort*)alloc((size_t)V_PREV * F_OUT * 2);   // 8.4 MB
    ushort* XBF   = (ushort*)alloc((size_t)V_PREV * F_IN * 2);    // 16.8 MB
    ushort* X1    = (ushort*)alloc((size_t)V_NEXT * F_OUT * 2);   // 33.6 MB
    ushort* G     = (ushort*)alloc((size_t)V_NEXT * F_OUT * 2);   // 33.6 MB
    // --- zeroed region (memsetAsync): cnt, psum1s, psq1s = 98304 ints ---
    int*    cnt   = (int*)   alloc(V_NEXT * 4);                   // 256 KB
    float*  psum1s= (float*) alloc(64 * 256 * 4);                 // 64 KB
    float*  psq1s = (float*) alloc(64 * 256 * 4);                 // 64 KB
    float*  sumA  = (float*) alloc(V_NEXT * 4);
    int*    offs  = (int*)   alloc(V_NEXT * 4);
    int*    cursor= (int*)   alloc(V_NEXT * 4);
    int*    bsum  = (int*)   alloc(256 * 4);
    int4*   E     = (int4*)  alloc((size_t)N_EDGE * 16);          // 8.4 MB
    int*    colof = (int*)   alloc(V_NEXT * 4);
    float*  valof = (float*) alloc(V_NEXT * 4);
    ushort* WresT = (ushort*)alloc(256 * 512 * 2);
    ushort* W0t   = (ushort*)alloc(512 * 512 * 2);
    ushort* W1cat = (ushort*)alloc(256 * 512 * 2);
    float*  biasUi= (float*) alloc(256 * 4);
    float*  psum0 = (float*) alloc(512 * 512 * 4);                // 1 MB
    float*  psq0  = (float*) alloc(512 * 512 * 4);                // 1 MB
    float*  sc0   = (float*) alloc(512 * 4);
    float*  sh0   = (float*) alloc(512 * 4);
    float*  sc1   = (float*) alloc(256 * 4);
    float*  sh1   = (float*) alloc(256 * 4);
    (void)ws_size; (void)in_sizes; (void)n_in; (void)out_size;

    // ---- K0: zero cnt + psum1s + psq1s (contiguous) ----
    hipMemsetAsync(cnt, 0, (size_t)98304 * 4, stream);

    // ---- K1: mega prep: weights + up-invert + hist + bn0 partials + XBF ----
    mega_prep_kernel<<<3840, 256, 0, stream>>>(W_res, Ui0_W, Uj0_W, Ui1_W, Uj1_W,
                                               Ui1_b, b_res,
                                               up_row, up_col, up_val,
                                               e_dst, x,
                                               WresT, W0t, W1cat, biasUi,
                                               colof, valof, cnt, psum0, psq0, XBF);

    // ---- K2: block scan ----
    scan_block_kernel<<<256, 256, 0, stream>>>(cnt, offs, bsum);

    // ---- K3: offset add + bn0 finish ----
    add_offs_bnfin_kernel<<<384, 256, 0, stream>>>(offs, bsum, cursor,
                                                   psum0, psq0, bn0_g, bn0_b, sc0, sh0);

    // ---- K4: GEMM0 (bf16 A, BK=64, blocks 0..767) + edge fill (768..2815) ----
    fill_gemm0_kernel<<<2816, 256, 0, stream>>>(e_src, e_dst, adjv, colof, valof,
                                                cursor, E,
                                                XBF, WresT, W0t, sc0, sh0,
                                                XW, XNJ, XNI);

    // ---- K5: ECC layer 0 aggregation + sumA + bn1 stats (persistent) ----
    gather0_kernel<<<2048, 256, 0, stream>>>(offs, cnt, E, colof, valof,
                                             XNJ, XNI, Ui0_b, Uj0_b,
                                             X1, sumA, psum1s, psq1s);

    // ---- K6: bn1 finish ----
    bn_finish_kernel<<<64, 256, 0, stream>>>(psum1s, psq1s, 64, 256, 1.0f / V_NEXT,
                                             bn1_g, bn1_b, sc1, sh1);

    // ---- K7: ECC layer 1 aggregation (commuted, persistent) ----
    gather1G_kernel<<<2048, 256, 0, stream>>>(offs, cnt, E, X1, sc1, sh1, G);

    // ---- K8: final GEMM: out = [H1|G] @ W1cat + biases + residual ----
    gemm_final_kernel<<<256, 512, 0, stream>>>(X1, G, W1cat, sc1, sh1,
                                               biasUi, Uj1_b, sumA,
                                               colof, valof, XW, out);
}